// Round 1
// baseline (236.774 us; speedup 1.0000x reference)
//
#include <hip/hip_runtime.h>

#define N_NODES 50000
#define F_IN    512
#define HID     128
#define OUT_F   64
#define NIDX    1000
#define E_NUM   800000
#define CAP     80      // bucket capacity; Poisson(16) => P(deg>80) ~ 3e-30

// ---------------------------------------------------------------------------
// GEMM1: XW0 = x @ W0   [50000,512] @ [512,128], fp32 vector, tiled.
// BM=64, BN=128 (full), BK=32. 256 threads; each computes 4 rows x 8 cols.
// ---------------------------------------------------------------------------
__global__ __launch_bounds__(256) void gemm1_kernel(const float* __restrict__ x,
                                                    const float* __restrict__ W0,
                                                    float* __restrict__ XW0) {
    __shared__ float xs[64][36];    // pad 32->36: stride-36 reads ~2-way (free)
    __shared__ float ws[32][132];   // pad 128->132

    const int t  = threadIdx.x;
    const int tx = t & 15;          // col group: cols tx*4..+3 and 64+tx*4..+3
    const int ty = t >> 4;          // row group: rows ty*4..ty*4+3
    const int m0 = blockIdx.x * 64;

    float acc[4][8];
#pragma unroll
    for (int i = 0; i < 4; ++i)
#pragma unroll
        for (int j = 0; j < 8; ++j) acc[i][j] = 0.f;

    for (int k0 = 0; k0 < F_IN; k0 += 32) {
        // ---- stage x tile: 64 rows x 32 cols (2048 floats / 256 thr = 2 float4)
        {
            const int r = t >> 2, f = t & 3;
            const int row = m0 + r;
            float4 v0 = make_float4(0.f, 0.f, 0.f, 0.f), v1 = v0;
            if (row < N_NODES) {
                const float* p = x + (size_t)row * F_IN + k0;
                v0 = *(const float4*)(p + f * 4);
                v1 = *(const float4*)(p + f * 4 + 16);
            }
            *(float4*)&xs[r][f * 4]      = v0;
            *(float4*)&xs[r][f * 4 + 16] = v1;
        }
        // ---- stage W0 tile: 32 rows x 128 cols (4096 floats / 256 thr = 4 float4)
        {
            const int kr = t >> 5;      // 0..7
            const int c4 = t & 31;      // col = c4*4
#pragma unroll
            for (int i = 0; i < 4; ++i) {
                const int kk = kr + i * 8;
                float4 v = *(const float4*)(W0 + (size_t)(k0 + kk) * HID + c4 * 4);
                *(float4*)&ws[kk][c4 * 4] = v;
            }
        }
        __syncthreads();

#pragma unroll 8
        for (int kk = 0; kk < 32; ++kk) {
            const float a0 = xs[ty * 4 + 0][kk];
            const float a1 = xs[ty * 4 + 1][kk];
            const float a2 = xs[ty * 4 + 2][kk];
            const float a3 = xs[ty * 4 + 3][kk];
            const float4 b0 = *(const float4*)&ws[kk][tx * 4];
            const float4 b1 = *(const float4*)&ws[kk][64 + tx * 4];
            acc[0][0] += a0 * b0.x; acc[0][1] += a0 * b0.y; acc[0][2] += a0 * b0.z; acc[0][3] += a0 * b0.w;
            acc[0][4] += a0 * b1.x; acc[0][5] += a0 * b1.y; acc[0][6] += a0 * b1.z; acc[0][7] += a0 * b1.w;
            acc[1][0] += a1 * b0.x; acc[1][1] += a1 * b0.y; acc[1][2] += a1 * b0.z; acc[1][3] += a1 * b0.w;
            acc[1][4] += a1 * b1.x; acc[1][5] += a1 * b1.y; acc[1][6] += a1 * b1.z; acc[1][7] += a1 * b1.w;
            acc[2][0] += a2 * b0.x; acc[2][1] += a2 * b0.y; acc[2][2] += a2 * b0.z; acc[2][3] += a2 * b0.w;
            acc[2][4] += a2 * b1.x; acc[2][5] += a2 * b1.y; acc[2][6] += a2 * b1.z; acc[2][7] += a2 * b1.w;
            acc[3][0] += a3 * b0.x; acc[3][1] += a3 * b0.y; acc[3][2] += a3 * b0.z; acc[3][3] += a3 * b0.w;
            acc[3][4] += a3 * b1.x; acc[3][5] += a3 * b1.y; acc[3][6] += a3 * b1.z; acc[3][7] += a3 * b1.w;
        }
        __syncthreads();
    }

#pragma unroll
    for (int i = 0; i < 4; ++i) {
        const int row = m0 + ty * 4 + i;
        if (row < N_NODES) {
            float* o = XW0 + (size_t)row * HID;
            *(float4*)(o + tx * 4)      = make_float4(acc[i][0], acc[i][1], acc[i][2], acc[i][3]);
            *(float4*)(o + 64 + tx * 4) = make_float4(acc[i][4], acc[i][5], acc[i][6], acc[i][7]);
        }
    }
}

// ---------------------------------------------------------------------------
// Bucket build: append edge id to bucket[dst] (counting sort, no fp atomics)
// ---------------------------------------------------------------------------
__global__ __launch_bounds__(256) void build_buckets_kernel(const int* __restrict__ edst,
                                                            int* __restrict__ counts,
                                                            int* __restrict__ buckets) {
    const int e = blockIdx.x * 256 + threadIdx.x;
    if (e >= E_NUM) return;
    const int d = edst[e];
    const int c = atomicAdd(&counts[d], 1);
    if (c < CAP) buckets[d * CAP + c] = e;
}

// ---------------------------------------------------------------------------
// Flag nodes whose h-row is needed: srcs of edges incident to idx nodes
// ---------------------------------------------------------------------------
__global__ __launch_bounds__(256) void flag_kernel(const int* __restrict__ idx,
                                                   const int* __restrict__ counts,
                                                   const int* __restrict__ buckets,
                                                   const int* __restrict__ esrc,
                                                   int* __restrict__ flags) {
    const int j = blockIdx.x * 256 + threadIdx.x;
    if (j >= NIDX) return;
    const int n = idx[j];
    const int deg = min(counts[n], CAP);
    for (int c = 0; c < deg; ++c) {
        const int e = buckets[n * CAP + c];
        flags[esrc[e]] = 1;
    }
}

// ---------------------------------------------------------------------------
// SPMM1 + ReLU (flagged dst only): H[n] = relu( sum_e w[e]*XW0[src[e]] )
// One 64-lane wave per node; 2 cols/lane.
// ---------------------------------------------------------------------------
__global__ __launch_bounds__(64) void spmm1_kernel(const float* __restrict__ XW0,
                                                   const int* __restrict__ counts,
                                                   const int* __restrict__ buckets,
                                                   const int* __restrict__ esrc,
                                                   const float* __restrict__ ew,
                                                   const int* __restrict__ flags,
                                                   float* __restrict__ H) {
    const int n = blockIdx.x;
    if (flags[n] == 0) return;
    const int lane = threadIdx.x;
    const int deg = min(counts[n], CAP);
    float acc0 = 0.f, acc1 = 0.f;
    for (int c = 0; c < deg; ++c) {
        const int e = buckets[n * CAP + c];
        const int s = esrc[e];
        const float wt = ew[e];
        const float* row = XW0 + (size_t)s * HID;
        acc0 += wt * row[lane];
        acc1 += wt * row[lane + 64];
    }
    H[(size_t)n * HID + lane]      = fmaxf(acc0, 0.f);
    H[(size_t)n * HID + lane + 64] = fmaxf(acc1, 0.f);
}

// ---------------------------------------------------------------------------
// SPMM2 (idx rows only) fused with GEMM2:
// agg = sum_e w[e]*H[src[e]]  (128) ; out[j] = agg @ W1  (64)
// ---------------------------------------------------------------------------
__global__ __launch_bounds__(64) void spmm2_kernel(const float* __restrict__ H,
                                                   const float* __restrict__ W1,
                                                   const int* __restrict__ idx,
                                                   const int* __restrict__ counts,
                                                   const int* __restrict__ buckets,
                                                   const int* __restrict__ esrc,
                                                   const float* __restrict__ ew,
                                                   float* __restrict__ outp) {
    __shared__ float aggs[HID];
    const int j = blockIdx.x;
    const int lane = threadIdx.x;
    const int n = idx[j];
    const int deg = min(counts[n], CAP);
    float acc0 = 0.f, acc1 = 0.f;
    for (int c = 0; c < deg; ++c) {
        const int e = buckets[n * CAP + c];
        const int s = esrc[e];
        const float wt = ew[e];
        const float* row = H + (size_t)s * HID;
        acc0 += wt * row[lane];
        acc1 += wt * row[lane + 64];
    }
    aggs[lane]      = acc0;
    aggs[lane + 64] = acc1;
    __syncthreads();
    float s = 0.f;
    for (int k = 0; k < HID; ++k) s += aggs[k] * W1[k * OUT_F + lane];
    outp[(size_t)j * OUT_F + lane] = s;
}

// ---------------------------------------------------------------------------
extern "C" void kernel_launch(void* const* d_in, const int* in_sizes, int n_in,
                              void* d_out, int out_size, void* d_ws, size_t ws_size,
                              hipStream_t stream) {
    const float* x    = (const float*)d_in[0];
    const float* W0   = (const float*)d_in[1];
    const float* W1   = (const float*)d_in[2];
    const float* ew   = (const float*)d_in[3];
    const int*   esrc = (const int*)d_in[4];
    const int*   edst = (const int*)d_in[5];
    const int*   idx  = (const int*)d_in[6];
    float* outp = (float*)d_out;

    // workspace layout (bytes)
    char* ws = (char*)d_ws;
    const size_t XW0_BYTES  = (size_t)N_NODES * HID * 4;   // 25,600,000
    const size_t H_BYTES    = (size_t)N_NODES * HID * 4;   // 25,600,000
    const size_t BKT_BYTES  = (size_t)N_NODES * CAP * 4;   // 16,000,000
    const size_t CNT_BYTES  = 204800;                      // 50000*4 padded
    float* XW0    = (float*)(ws);
    float* H      = (float*)(ws + XW0_BYTES);
    int*   bkts   = (int*)  (ws + XW0_BYTES + H_BYTES);
    int*   counts = (int*)  (ws + XW0_BYTES + H_BYTES + BKT_BYTES);
    int*   flags  = (int*)  (ws + XW0_BYTES + H_BYTES + BKT_BYTES + CNT_BYTES);

    // zero counts + flags (contiguous)
    hipMemsetAsync(counts, 0, 2 * CNT_BYTES, stream);

    build_buckets_kernel<<<(E_NUM + 255) / 256, 256, 0, stream>>>(edst, counts, bkts);
    flag_kernel<<<(NIDX + 255) / 256, 256, 0, stream>>>(idx, counts, bkts, esrc, flags);
    gemm1_kernel<<<(N_NODES + 63) / 64, 256, 0, stream>>>(x, W0, XW0);
    spmm1_kernel<<<N_NODES, 64, 0, stream>>>(XW0, counts, bkts, esrc, ew, flags, H);
    spmm2_kernel<<<NIDX, 64, 0, stream>>>(H, W1, idx, counts, bkts, esrc, ew, outp);
}

// Round 2
// 167.636 us; speedup vs baseline: 1.4124x; 1.4124x over previous
//
#include <hip/hip_runtime.h>
#include <hip/hip_bf16.h>

#define N_NODES 50000
#define F_IN    512
#define HID     128
#define OUT_F   64
#define NIDX    1000
#define E_NUM   800000
#define CAP     48      // Poisson(16): P(deg>48) ~ 1e-11 per node

typedef __attribute__((ext_vector_type(8))) short short8;
typedef __attribute__((ext_vector_type(4))) float f32x4;

__device__ inline ushort f2bf(float f) {
    __hip_bfloat16 h = __float2bfloat16(f);   // RNE
    return *reinterpret_cast<ushort*>(&h);
}
__device__ inline float bf2f(ushort u) {
    return __uint_as_float(((uint)u) << 16);
}

// ---------------------------------------------------------------------------
// W0t[n][k] = bf16(W0[k][n])   (128 x 512, 131 KB, L2-resident thereafter)
// ---------------------------------------------------------------------------
__global__ __launch_bounds__(256) void w0t_kernel(const float* __restrict__ W0,
                                                  ushort* __restrict__ W0t) {
    const int t = blockIdx.x * 256 + threadIdx.x;   // 65536 total
    const int n = t & 127, k = t >> 7;              // coalesced read of W0[k][n]
    W0t[(size_t)n * F_IN + k] = f2bf(W0[(size_t)k * HID + n]);
}

// ---------------------------------------------------------------------------
// GEMM1 (bf16 MFMA): XW0b = bf16( x @ W0 )   [50000,512]x[512,128]
// BM=128, BN=128, BK=64; 256 thr = 4 waves in 2x2 grid; wave tile 64x64.
// ---------------------------------------------------------------------------
__global__ __launch_bounds__(256) void gemm1_mfma(const float* __restrict__ x,
                                                  const ushort* __restrict__ W0t,
                                                  ushort* __restrict__ XW0b) {
    __shared__ ushort As[128][72];   // +8 pad: fragment reads spread banks (2-way max)
    __shared__ ushort Bs[128][72];

    const int t = threadIdx.x;
    const int m0 = blockIdx.x * 128;
    const int w = t >> 6, lane = t & 63;
    const int wr = w >> 1, wc = w & 1;          // 2x2 wave grid
    const int lr = lane & 15, lk = lane >> 4;   // frag row/col, k-group

    f32x4 acc[4][4] = {};

    for (int k0 = 0; k0 < F_IN; k0 += 64) {
        // ---- stage A: x[m0..+127][k0..+63] fp32 -> bf16 (8 float4/thread)
#pragma unroll
        for (int i = 0; i < 8; ++i) {
            const int id = i * 256 + t;
            const int row = id >> 4, c4 = id & 15;
            const int grow = m0 + row;
            float4 v = make_float4(0.f, 0.f, 0.f, 0.f);
            if (grow < N_NODES)
                v = *(const float4*)(x + (size_t)grow * F_IN + k0 + c4 * 4);
            ushort4 p;
            p.x = f2bf(v.x); p.y = f2bf(v.y); p.z = f2bf(v.z); p.w = f2bf(v.w);
            *(ushort4*)&As[row][c4 * 4] = p;
        }
        // ---- stage B: W0t[n][k0..+63] straight bf16 copy (4 x 16B/thread)
#pragma unroll
        for (int i = 0; i < 4; ++i) {
            const int id = i * 256 + t;
            const int row = id >> 3, c8 = id & 7;
            uint4 v = *(const uint4*)(W0t + (size_t)row * F_IN + k0 + c8 * 8);
            *(uint4*)&Bs[row][c8 * 8] = v;
        }
        __syncthreads();

#pragma unroll
        for (int kk = 0; kk < 2; ++kk) {
            short8 a[4], b[4];
#pragma unroll
            for (int mi = 0; mi < 4; ++mi)
                a[mi] = *(const short8*)&As[wr * 64 + mi * 16 + lr][kk * 32 + lk * 8];
#pragma unroll
            for (int ni = 0; ni < 4; ++ni)
                b[ni] = *(const short8*)&Bs[wc * 64 + ni * 16 + lr][kk * 32 + lk * 8];
#pragma unroll
            for (int mi = 0; mi < 4; ++mi)
#pragma unroll
                for (int ni = 0; ni < 4; ++ni)
                    acc[mi][ni] = __builtin_amdgcn_mfma_f32_16x16x32_bf16(
                        a[mi], b[ni], acc[mi][ni], 0, 0, 0);
        }
        __syncthreads();
    }

    // epilogue: C/D layout col=lane&15, row=(lane>>4)*4+reg  [m89/m91]
#pragma unroll
    for (int mi = 0; mi < 4; ++mi)
#pragma unroll
        for (int r = 0; r < 4; ++r) {
            const int grow = m0 + wr * 64 + mi * 16 + lk * 4 + r;
            if (grow < N_NODES) {
                ushort* orow = XW0b + (size_t)grow * HID + wc * 64;
#pragma unroll
                for (int ni = 0; ni < 4; ++ni)
                    orow[ni * 16 + lr] = f2bf(acc[mi][ni][r]);
            }
        }
}

// ---------------------------------------------------------------------------
// Bucket build: bkt[dst][c] = (src, weight) — no edge-id indirection later
// ---------------------------------------------------------------------------
__global__ __launch_bounds__(256) void build_buckets_kernel(const int* __restrict__ esrc,
                                                            const int* __restrict__ edst,
                                                            const float* __restrict__ ew,
                                                            int* __restrict__ counts,
                                                            int2* __restrict__ bkt) {
    const int e = blockIdx.x * 256 + threadIdx.x;
    if (e >= E_NUM) return;
    const int d = edst[e];
    const int c = atomicAdd(&counts[d], 1);
    if (c < CAP) bkt[(size_t)d * CAP + c] = make_int2(esrc[e], __float_as_int(ew[e]));
}

// ---------------------------------------------------------------------------
__global__ __launch_bounds__(256) void flag_kernel(const int* __restrict__ idx,
                                                   const int* __restrict__ counts,
                                                   const int2* __restrict__ bkt,
                                                   int* __restrict__ flags) {
    const int j = blockIdx.x * 256 + threadIdx.x;
    if (j >= NIDX) return;
    const int n = idx[j];
    const int deg = min(counts[n], CAP);
    for (int c = 0; c < deg; ++c)
        flags[bkt[(size_t)n * CAP + c].x] = 1;
}

__global__ __launch_bounds__(256) void compact_kernel(const int* __restrict__ flags,
                                                      int* __restrict__ list,
                                                      int* __restrict__ nflag) {
    const int n = blockIdx.x * 256 + threadIdx.x;
    if (n < N_NODES && flags[n])
        list[atomicAdd(nflag, 1)] = n;
}

// ---------------------------------------------------------------------------
// SPMM1+ReLU over compacted flagged nodes; 1 wave/node, 2 cols/lane (bf16 io)
// ---------------------------------------------------------------------------
__global__ __launch_bounds__(256) void spmm1_kernel(const ushort* __restrict__ XW0b,
                                                    const int* __restrict__ list,
                                                    const int* __restrict__ nflag,
                                                    const int2* __restrict__ bkt,
                                                    const int* __restrict__ counts,
                                                    ushort* __restrict__ H) {
    const int lane = threadIdx.x & 63;
    const int nf = *nflag;
    const int nw = gridDim.x * 4;
    for (int wdx = blockIdx.x * 4 + (threadIdx.x >> 6); wdx < nf; wdx += nw) {
        const int n = list[wdx];
        const int deg = min(counts[n], CAP);
        float a0 = 0.f, a1 = 0.f;
        for (int c = 0; c < deg; ++c) {
            const int2 p = bkt[(size_t)n * CAP + c];          // wave-uniform (scalar)
            const float wt = __int_as_float(p.y);
            const uint v = *(const uint*)(XW0b + (size_t)p.x * HID + 2 * lane);
            a0 += wt * bf2f((ushort)(v & 0xffffu));
            a1 += wt * bf2f((ushort)(v >> 16));
        }
        const uint o = (uint)f2bf(fmaxf(a0, 0.f)) | ((uint)f2bf(fmaxf(a1, 0.f)) << 16);
        *(uint*)(H + (size_t)n * HID + 2 * lane) = o;
    }
}

// ---------------------------------------------------------------------------
// SPMM2 (idx rows) fused with GEMM2: out[j] = (sum w*H[src]) @ W1
// ---------------------------------------------------------------------------
__global__ __launch_bounds__(64) void spmm2_kernel(const ushort* __restrict__ H,
                                                   const float* __restrict__ W1,
                                                   const int* __restrict__ idx,
                                                   const int* __restrict__ counts,
                                                   const int2* __restrict__ bkt,
                                                   float* __restrict__ outp) {
    __shared__ float aggs[HID];
    const int j = blockIdx.x, lane = threadIdx.x;
    const int n = idx[j];
    const int deg = min(counts[n], CAP);
    float a0 = 0.f, a1 = 0.f;
    for (int c = 0; c < deg; ++c) {
        const int2 p = bkt[(size_t)n * CAP + c];
        const float wt = __int_as_float(p.y);
        const uint v = *(const uint*)(H + (size_t)p.x * HID + 2 * lane);
        a0 += wt * bf2f((ushort)(v & 0xffffu));
        a1 += wt * bf2f((ushort)(v >> 16));
    }
    aggs[2 * lane] = a0; aggs[2 * lane + 1] = a1;
    __syncthreads();
    float s = 0.f;
#pragma unroll 8
    for (int k = 0; k < HID; ++k) s += aggs[k] * W1[k * OUT_F + lane];
    outp[(size_t)j * OUT_F + lane] = s;
}

// ---------------------------------------------------------------------------
extern "C" void kernel_launch(void* const* d_in, const int* in_sizes, int n_in,
                              void* d_out, int out_size, void* d_ws, size_t ws_size,
                              hipStream_t stream) {
    const float* x    = (const float*)d_in[0];
    const float* W0   = (const float*)d_in[1];
    const float* W1   = (const float*)d_in[2];
    const float* ew   = (const float*)d_in[3];
    const int*   esrc = (const int*)d_in[4];
    const int*   edst = (const int*)d_in[5];
    const int*   idx  = (const int*)d_in[6];
    float* outp = (float*)d_out;

    char* ws = (char*)d_ws;
    ushort* XW0b  = (ushort*)(ws);                 // 12,800,000 B
    ushort* H     = (ushort*)(ws + 12800000);      // 12,800,000 B
    int2*   bkt   = (int2*)  (ws + 25600000);      // 19,200,000 B
    ushort* W0t   = (ushort*)(ws + 44800000);      //    131,072 B
    int*    counts= (int*)   (ws + 44931072);      //    204,800 B
    int*    flags = (int*)   (ws + 45135872);      //    204,800 B
    int*    nflag = (int*)   (ws + 45340672);      //        256 B
    int*    list  = (int*)   (ws + 45340928);      //    204,800 B

    hipMemsetAsync(counts, 0, 204800 + 204800 + 256, stream);  // counts+flags+nflag

    w0t_kernel        <<<(F_IN * HID) / 256, 256, 0, stream>>>(W0, W0t);
    build_buckets_kernel<<<(E_NUM + 255) / 256, 256, 0, stream>>>(esrc, edst, ew, counts, bkt);
    flag_kernel       <<<(NIDX + 255) / 256, 256, 0, stream>>>(idx, counts, bkt, flags);
    compact_kernel    <<<(N_NODES + 255) / 256, 256, 0, stream>>>(flags, list, nflag);
    gemm1_mfma        <<<(N_NODES + 127) / 128, 256, 0, stream>>>(x, W0t, XW0b);
    spmm1_kernel      <<<1024, 256, 0, stream>>>(XW0b, list, nflag, bkt, counts, H);
    spmm2_kernel      <<<NIDX, 64, 0, stream>>>(H, W1, idx, counts, bkt, outp);
}

// Round 3
// 161.222 us; speedup vs baseline: 1.4686x; 1.0398x over previous
//
#include <hip/hip_runtime.h>
#include <hip/hip_bf16.h>

#define N_NODES 50000
#define F_IN    512
#define HID     128
#define OUT_F   64
#define NIDX    1000
#define E_NUM   800000
#define CAP     48       // Poisson(16): P(deg>48) ~ 1e-11 per node
#define MAXFLAG 20480    // flagged-node capacity (expected ~13.7k, 28 sigma margin)

typedef __attribute__((ext_vector_type(8))) short short8;
typedef __attribute__((ext_vector_type(4))) float f32x4;

__device__ inline ushort f2bf(float f) {
    __hip_bfloat16 h = __float2bfloat16(f);   // RNE
    return *reinterpret_cast<ushort*>(&h);
}
__device__ inline float bf2f(ushort u) {
    return __uint_as_float(((uint)u) << 16);
}

// ---------------------------------------------------------------------------
// prep: W0t[n][k] = bf16(W0[k][n]) via LDS transpose tiles (both sides
// coalesced), + jmap[idx[j]] = j+1 (dup-idx winner arbitrary; output invariant)
// ---------------------------------------------------------------------------
__global__ __launch_bounds__(256) void prep_kernel(const float* __restrict__ W0,
                                                   ushort* __restrict__ W0t,
                                                   const int* __restrict__ idx,
                                                   int* __restrict__ jmap) {
    const int b = blockIdx.x;
    if (b < 64) {   // 16 k-tiles x 4 n-tiles of 32x32
        __shared__ float tl[32][33];
        const int k0 = (b & 15) * 32, n0 = (b >> 4) * 32;
        const int tx = threadIdx.x & 31, ty = threadIdx.x >> 5;   // ty 0..7
#pragma unroll
        for (int i = 0; i < 4; ++i)
            tl[ty + i * 8][tx] = W0[(size_t)(k0 + ty + i * 8) * HID + n0 + tx];
        __syncthreads();
#pragma unroll
        for (int i = 0; i < 4; ++i) {
            const int n = ty + i * 8;
            W0t[(size_t)(n0 + n) * F_IN + k0 + tx] = f2bf(tl[tx][n]);
        }
    } else {        // blocks 64..67: mark idx reps
        const int j = (b - 64) * 256 + threadIdx.x;
        if (j < NIDX) jmap[idx[j]] = j + 1;
    }
}

// ---------------------------------------------------------------------------
// GEMM1 (bf16 MFMA): XW0b = bf16(x @ W0)  [50000,512]x[512,128]
// BM=64,BN=128,BK=64; 4 waves 2x2 (wave tile 32x64); double-buffered LDS,
// XOR chunk-swizzle (16B chunk ^ row&7) on both ds_write and ds_read.
// ---------------------------------------------------------------------------
__global__ __launch_bounds__(256) void gemm1_mfma(const float* __restrict__ x,
                                                  const ushort* __restrict__ W0t,
                                                  ushort* __restrict__ XW0b) {
    __shared__ ushort As[2 * 64 * 64];    // 16 KB: [buf][row64][64] bf16
    __shared__ ushort Bs[2 * 128 * 64];   // 32 KB: [buf][row128][64] bf16

    const int t = threadIdx.x;
    const int m0 = blockIdx.x * 64;
    const int w = t >> 6, lane = t & 63;
    const int wr = w >> 1, wc = w & 1;
    const int lr = lane & 15, lk = lane >> 4;

    f32x4 acc[2][4] = {};
    float4 fa[4];
    uint4  fb[4];

    // staging coords (per i in 0..3):
    //   A: row = i*16 + (t>>4), 8B at byte-chunk (t&15)  -> swizzled 16B chunk
    //   B: row = i*32 + (t>>3), 16B chunk (t&7)
    const int a_r = t >> 4, a_c4 = t & 15;
    const int b_r = t >> 3, b_c8 = t & 7;

    auto issue_loads = [&](int k0) {
#pragma unroll
        for (int i = 0; i < 4; ++i) {
            int grow = m0 + i * 16 + a_r;
            grow = grow < N_NODES ? grow : N_NODES - 1;   // clamp (rows never stored OOB)
            fa[i] = *(const float4*)(x + (size_t)grow * F_IN + k0 + a_c4 * 4);
            fb[i] = *(const uint4*)(W0t + (size_t)(i * 32 + b_r) * F_IN + k0 + b_c8 * 8);
        }
    };
    auto write_tile = [&](int buf) {
#pragma unroll
        for (int i = 0; i < 4; ++i) {
            const int ar = i * 16 + a_r;
            ushort4 p;
            p.x = f2bf(fa[i].x); p.y = f2bf(fa[i].y); p.z = f2bf(fa[i].z); p.w = f2bf(fa[i].w);
            *(ushort4*)&As[buf * 4096 + ar * 64 + (((a_c4 >> 1) ^ (ar & 7)) << 3) + ((a_c4 & 1) << 2)] = p;
            const int br = i * 32 + b_r;
            *(uint4*)&Bs[buf * 8192 + br * 64 + ((b_c8 ^ (br & 7)) << 3)] = fb[i];
        }
    };

    issue_loads(0);
    write_tile(0);
    __syncthreads();

    for (int kt = 0; kt < 8; ++kt) {
        if (kt < 7) issue_loads((kt + 1) << 6);   // T14: issue early
        const int cur = kt & 1;
#pragma unroll
        for (int kk = 0; kk < 2; ++kk) {
            short8 a[2], b[4];
#pragma unroll
            for (int mi = 0; mi < 2; ++mi) {
                const int R = wr * 32 + mi * 16 + lr;
                a[mi] = *(const short8*)&As[cur * 4096 + R * 64 + (((kk * 4 + lk) ^ (R & 7)) << 3)];
            }
#pragma unroll
            for (int ni = 0; ni < 4; ++ni) {
                const int R = wc * 64 + ni * 16 + lr;
                b[ni] = *(const short8*)&Bs[cur * 8192 + R * 64 + (((kk * 4 + lk) ^ (R & 7)) << 3)];
            }
#pragma unroll
            for (int mi = 0; mi < 2; ++mi)
#pragma unroll
                for (int ni = 0; ni < 4; ++ni)
                    acc[mi][ni] = __builtin_amdgcn_mfma_f32_16x16x32_bf16(
                        a[mi], b[ni], acc[mi][ni], 0, 0, 0);
        }
        if (kt < 7) write_tile((kt + 1) & 1);     // T14: write late
        __syncthreads();
    }

    // epilogue: C/D layout col=lane&15, row=(lane>>4)*4+reg
#pragma unroll
    for (int mi = 0; mi < 2; ++mi)
#pragma unroll
        for (int r = 0; r < 4; ++r) {
            const int grow = m0 + wr * 32 + mi * 16 + lk * 4 + r;
            if (grow < N_NODES) {
                ushort* orow = XW0b + (size_t)grow * HID + wc * 64;
#pragma unroll
                for (int ni = 0; ni < 4; ++ni)
                    orow[ni * 16 + lr] = f2bf(acc[mi][ni][r]);
            }
        }
}

// ---------------------------------------------------------------------------
// scan 1: append edges whose dst is an idx node into dense 1000-slot buckets
// ---------------------------------------------------------------------------
__global__ __launch_bounds__(256) void bucket_idx_kernel(const int* __restrict__ esrc,
                                                         const int* __restrict__ edst,
                                                         const float* __restrict__ ew,
                                                         const int* __restrict__ jmap,
                                                         int* __restrict__ countsA,
                                                         int2* __restrict__ bktA) {
    const int e = blockIdx.x * 256 + threadIdx.x;
    if (e >= E_NUM) return;
    const int rep = jmap[edst[e]];
    if (rep) {
        const int r = rep - 1;
        const int c = atomicAdd(&countsA[r], 1);
        if (c < CAP) bktA[(size_t)r * CAP + c] = make_int2(esrc[e], __float_as_int(ew[e]));
    }
}

// flag srcs of idx-in-edges (only the rep j walks its bucket)
__global__ __launch_bounds__(256) void flag_kernel(const int* __restrict__ idx,
                                                   const int* __restrict__ jmap,
                                                   const int* __restrict__ countsA,
                                                   const int2* __restrict__ bktA,
                                                   int* __restrict__ flags) {
    const int j = blockIdx.x * 256 + threadIdx.x;
    if (j >= NIDX) return;
    if (jmap[idx[j]] != j + 1) return;   // dup: not the rep
    const int deg = min(countsA[j], CAP);
    for (int c = 0; c < deg; ++c)
        flags[bktA[(size_t)j * CAP + c].x] = 1;
}

// compact flagged nodes -> list; flags[n] becomes slot+1
__global__ __launch_bounds__(256) void compact_kernel(int* __restrict__ flags,
                                                      int* __restrict__ list,
                                                      int* __restrict__ nflag) {
    const int n = blockIdx.x * 256 + threadIdx.x;
    if (n < N_NODES && flags[n]) {
        const int s = atomicAdd(nflag, 1);
        flags[n] = s + 1;
        list[s] = n;
    }
}

// scan 2: append edges whose dst is flagged into dense slot buckets
__global__ __launch_bounds__(256) void bucket_flag_kernel(const int* __restrict__ esrc,
                                                          const int* __restrict__ edst,
                                                          const float* __restrict__ ew,
                                                          const int* __restrict__ flags,
                                                          int* __restrict__ countsB,
                                                          int2* __restrict__ bktB) {
    const int e = blockIdx.x * 256 + threadIdx.x;
    if (e >= E_NUM) return;
    const int s = flags[edst[e]];
    if (s) {
        const int c = atomicAdd(&countsB[s - 1], 1);
        if (c < CAP) bktB[(size_t)(s - 1) * CAP + c] = make_int2(esrc[e], __float_as_int(ew[e]));
    }
}

// ---------------------------------------------------------------------------
// SPMM1+ReLU over compacted flagged nodes; 1 wave/node, 2 cols/lane (bf16 io)
// ---------------------------------------------------------------------------
__global__ __launch_bounds__(256) void spmm1_kernel(const ushort* __restrict__ XW0b,
                                                    const int* __restrict__ list,
                                                    const int* __restrict__ nflag,
                                                    const int* __restrict__ countsB,
                                                    const int2* __restrict__ bktB,
                                                    ushort* __restrict__ H) {
    const int lane = threadIdx.x & 63;
    const int nf = *nflag;
    const int nw = gridDim.x * 4;
    for (int wdx = blockIdx.x * 4 + (threadIdx.x >> 6); wdx < nf; wdx += nw) {
        const int n = list[wdx];
        const int deg = min(countsB[wdx], CAP);
        float a0 = 0.f, a1 = 0.f;
        for (int c = 0; c < deg; ++c) {
            const int2 p = bktB[(size_t)wdx * CAP + c];       // wave-uniform
            const float wt = __int_as_float(p.y);
            const uint v = *(const uint*)(XW0b + (size_t)p.x * HID + 2 * lane);
            a0 += wt * bf2f((ushort)(v & 0xffffu));
            a1 += wt * bf2f((ushort)(v >> 16));
        }
        const uint o = (uint)f2bf(fmaxf(a0, 0.f)) | ((uint)f2bf(fmaxf(a1, 0.f)) << 16);
        *(uint*)(H + (size_t)n * HID + 2 * lane) = o;
    }
}

// ---------------------------------------------------------------------------
// SPMM2 (idx rows) fused with GEMM2: out[j] = (sum w*H[src]) @ W1
// ---------------------------------------------------------------------------
__global__ __launch_bounds__(64) void spmm2_kernel(const ushort* __restrict__ H,
                                                   const float* __restrict__ W1,
                                                   const int* __restrict__ idx,
                                                   const int* __restrict__ jmap,
                                                   const int* __restrict__ countsA,
                                                   const int2* __restrict__ bktA,
                                                   float* __restrict__ outp) {
    __shared__ float aggs[HID];
    const int j = blockIdx.x, lane = threadIdx.x;
    const int r = jmap[idx[j]] - 1;       // rep slot (shared by dup idx entries)
    const int deg = min(countsA[r], CAP);
    float a0 = 0.f, a1 = 0.f;
    for (int c = 0; c < deg; ++c) {
        const int2 p = bktA[(size_t)r * CAP + c];
        const float wt = __int_as_float(p.y);
        const uint v = *(const uint*)(H + (size_t)p.x * HID + 2 * lane);
        a0 += wt * bf2f((ushort)(v & 0xffffu));
        a1 += wt * bf2f((ushort)(v >> 16));
    }
    aggs[2 * lane] = a0; aggs[2 * lane + 1] = a1;
    __syncthreads();
    float s = 0.f;
#pragma unroll 8
    for (int k = 0; k < HID; ++k) s += aggs[k] * W1[k * OUT_F + lane];
    outp[(size_t)j * OUT_F + lane] = s;
}

// ---------------------------------------------------------------------------
extern "C" void kernel_launch(void* const* d_in, const int* in_sizes, int n_in,
                              void* d_out, int out_size, void* d_ws, size_t ws_size,
                              hipStream_t stream) {
    const float* x    = (const float*)d_in[0];
    const float* W0   = (const float*)d_in[1];
    const float* W1   = (const float*)d_in[2];
    const float* ew   = (const float*)d_in[3];
    const int*   esrc = (const int*)d_in[4];
    const int*   edst = (const int*)d_in[5];
    const int*   idx  = (const int*)d_in[6];
    float* outp = (float*)d_out;

    char* ws = (char*)d_ws;
    ushort* XW0b   = (ushort*)(ws);                      // 12,800,000
    ushort* H      = (ushort*)(ws + 12800000);           // 12,800,000
    ushort* W0t    = (ushort*)(ws + 25600000);           //    131,072
    int2*   bktA   = (int2*)  (ws + 25731072);           //    384,000
    int2*   bktB   = (int2*)  (ws + 26115072);           //  7,864,320
    int*    list   = (int*)   (ws + 33979392);           //     81,920
    // zeroed control block (contiguous):
    char*   zbase  = ws + 34061312;
    int*    countsA = (int*)(zbase);                     //      4,096
    int*    countsB = (int*)(zbase + 4096);              //     81,920
    int*    flags   = (int*)(zbase + 86016);             //    200,000
    int*    jmap    = (int*)(zbase + 286016);            //    200,000
    int*    nflag   = (int*)(zbase + 486016);            //        256
    hipMemsetAsync(zbase, 0, 486272, stream);

    prep_kernel       <<<68, 256, 0, stream>>>(W0, W0t, idx, jmap);
    bucket_idx_kernel <<<(E_NUM + 255) / 256, 256, 0, stream>>>(esrc, edst, ew, jmap, countsA, bktA);
    flag_kernel       <<<(NIDX + 255) / 256, 256, 0, stream>>>(idx, jmap, countsA, bktA, flags);
    compact_kernel    <<<(N_NODES + 255) / 256, 256, 0, stream>>>(flags, list, nflag);
    bucket_flag_kernel<<<(E_NUM + 255) / 256, 256, 0, stream>>>(esrc, edst, ew, flags, countsB, bktB);
    gemm1_mfma        <<<(N_NODES + 63) / 64, 256, 0, stream>>>(x, W0t, XW0b);
    spmm1_kernel      <<<1024, 256, 0, stream>>>(XW0b, list, nflag, countsB, bktB, H);
    spmm2_kernel      <<<NIDX, 64, 0, stream>>>(H, W1, idx, jmap, countsA, bktA, outp);
}

// Round 4
// 148.677 us; speedup vs baseline: 1.5925x; 1.0844x over previous
//
#include <hip/hip_runtime.h>
#include <hip/hip_bf16.h>

#define N_NODES 50000
#define F_IN    512
#define HID     128
#define OUT_F   64
#define NIDX    1000
#define E_NUM   800000
#define CAP     48       // Poisson(16): P(deg>48) ~ 1e-11 per node
#define MAXFLAG 20480    // flagged-node capacity (expected ~13.6k)

typedef __attribute__((ext_vector_type(8))) short short8;
typedef __attribute__((ext_vector_type(4))) float f32x4;

__device__ inline ushort f2bf(float f) {
    __hip_bfloat16 h = __float2bfloat16(f);   // RNE
    return *reinterpret_cast<ushort*>(&h);
}
__device__ inline float bf2f(ushort u) {
    return __uint_as_float(((uint)u) << 16);
}
__device__ inline short8 pack_bf16x8(float4 a, float4 b) {
    short8 r;
    r[0] = (short)f2bf(a.x); r[1] = (short)f2bf(a.y);
    r[2] = (short)f2bf(a.z); r[3] = (short)f2bf(a.w);
    r[4] = (short)f2bf(b.x); r[5] = (short)f2bf(b.y);
    r[6] = (short)f2bf(b.z); r[7] = (short)f2bf(b.w);
    return r;
}

// ---------------------------------------------------------------------------
// prep: W0t[n][k] = bf16(W0[k][n]) via LDS transpose; jmap[idx[j]] = j+1
// ---------------------------------------------------------------------------
__global__ __launch_bounds__(256) void prep_kernel(const float* __restrict__ W0,
                                                   ushort* __restrict__ W0t,
                                                   const int* __restrict__ idx,
                                                   int* __restrict__ jmap) {
    const int b = blockIdx.x;
    if (b < 64) {   // 16 k-tiles x 4 n-tiles of 32x32
        __shared__ float tl[32][33];
        const int k0 = (b & 15) * 32, n0 = (b >> 4) * 32;
        const int tx = threadIdx.x & 31, ty = threadIdx.x >> 5;   // ty 0..7
#pragma unroll
        for (int i = 0; i < 4; ++i)
            tl[ty + i * 8][tx] = W0[(size_t)(k0 + ty + i * 8) * HID + n0 + tx];
        __syncthreads();
#pragma unroll
        for (int i = 0; i < 4; ++i) {
            const int n = ty + i * 8;
            W0t[(size_t)(n0 + n) * F_IN + k0 + tx] = f2bf(tl[tx][n]);
        }
    } else {        // blocks 64..67: mark idx reps
        const int j = (b - 64) * 256 + threadIdx.x;
        if (j < NIDX) jmap[idx[j]] = j + 1;
    }
}

// ---------------------------------------------------------------------------
// GEMM1, LDS-free: XW0b = bf16(x @ W0). Each wave owns 32 rows x 128 cols,
// K=512. A fragments (8 consecutive k, 32B fp32) loaded straight from x;
// B fragments (16B bf16) straight from L2-resident W0t. Register dbuf,
// no barriers in main loop. Epilogue: per-wave LDS transpose -> dwordx4.
// ---------------------------------------------------------------------------
__global__ __launch_bounds__(256, 2) void gemm1_direct(const float* __restrict__ x,
                                                       const ushort* __restrict__ W0t,
                                                       ushort* __restrict__ XW0b) {
    __shared__ float eps[4][16][132];           // 33,792 B epilogue buffers

    const int t = threadIdx.x;
    const int w = t >> 6, lane = t & 63;
    const int gw = blockIdx.x * 4 + w;          // 0..1563 (last is dummy)
    const int lr = lane & 15, lk = lane >> 4;
    const int m0 = gw * 32;

    int r0 = m0 + lr;      if (r0 > N_NODES - 1) r0 = N_NODES - 1;
    int r1 = m0 + 16 + lr; if (r1 > N_NODES - 1) r1 = N_NODES - 1;
    const float*  xa0 = x + (size_t)r0 * F_IN + lk * 8;
    const float*  xa1 = x + (size_t)r1 * F_IN + lk * 8;
    const ushort* wb  = W0t + (size_t)lr * F_IN + lk * 8;

    f32x4 acc[2][8] = {};
    float4 A[2][2][2];          // [buf][mi][half]
    uint4  B[2][8];             // [buf][ni]

    auto loadk = [&](int ks, int buf) {
        A[buf][0][0] = *(const float4*)(xa0 + ks * 32);
        A[buf][0][1] = *(const float4*)(xa0 + ks * 32 + 4);
        A[buf][1][0] = *(const float4*)(xa1 + ks * 32);
        A[buf][1][1] = *(const float4*)(xa1 + ks * 32 + 4);
#pragma unroll
        for (int ni = 0; ni < 8; ++ni)
            B[buf][ni] = *(const uint4*)(wb + (size_t)ni * 16 * F_IN + ks * 32);
    };

    loadk(0, 0);
#pragma unroll
    for (int ks = 0; ks < 16; ++ks) {
        const int cur = ks & 1;
        if (ks < 15) loadk(ks + 1, cur ^ 1);      // prefetch next k-step
        const short8 a0 = pack_bf16x8(A[cur][0][0], A[cur][0][1]);
        const short8 a1 = pack_bf16x8(A[cur][1][0], A[cur][1][1]);
#pragma unroll
        for (int ni = 0; ni < 8; ++ni) {
            const short8 bs = *(const short8*)&B[cur][ni];
            acc[0][ni] = __builtin_amdgcn_mfma_f32_16x16x32_bf16(a0, bs, acc[0][ni], 0, 0, 0);
            acc[1][ni] = __builtin_amdgcn_mfma_f32_16x16x32_bf16(a1, bs, acc[1][ni], 0, 0, 0);
        }
    }

    // epilogue: acc (col=lr, row=lk*4+reg) -> LDS -> coalesced bf16 rows
#pragma unroll
    for (int mi = 0; mi < 2; ++mi) {
        __syncthreads();                          // guard eps reuse
        float* ep = &eps[w][0][0];
#pragma unroll
        for (int ni = 0; ni < 8; ++ni)
#pragma unroll
            for (int r = 0; r < 4; ++r)
                ep[(lk * 4 + r) * 132 + ni * 16 + lr] = acc[mi][ni][r];
        __syncthreads();
        const int rr = lane >> 2, cg = lane & 3;  // row, 32-col group
        const int grow = m0 + mi * 16 + rr;
        float vv[32];
#pragma unroll
        for (int j = 0; j < 8; ++j)
            *(float4*)&vv[j * 4] = *(const float4*)&ep[rr * 132 + cg * 32 + j * 4];
        if (grow < N_NODES) {
            ushort us[32];
#pragma unroll
            for (int j = 0; j < 32; ++j) us[j] = f2bf(vv[j]);
#pragma unroll
            for (int k = 0; k < 4; ++k)
                *(uint4*)(XW0b + (size_t)grow * HID + cg * 32 + k * 8) = *(const uint4*)&us[k * 8];
        }
    }
}

// ---------------------------------------------------------------------------
// scan 1 (4 edges/thread): append idx-dst edges into dense 1000-slot buckets
// ---------------------------------------------------------------------------
__global__ __launch_bounds__(256) void bucket_idx_kernel(const int* __restrict__ esrc,
                                                         const int* __restrict__ edst,
                                                         const float* __restrict__ ew,
                                                         const int* __restrict__ jmap,
                                                         int* __restrict__ countsA,
                                                         int2* __restrict__ bktA) {
    const int e0 = (blockIdx.x * 256 + threadIdx.x) * 4;
    if (e0 >= E_NUM) return;
    const int4 d4 = *(const int4*)(edst + e0);
#define DOIT(J, DD) { const int rep = jmap[DD]; if (rep) { \
        const int r = rep - 1; const int c = atomicAdd(&countsA[r], 1); \
        if (c < CAP) bktA[(size_t)r * CAP + c] = make_int2(esrc[e0 + J], __float_as_int(ew[e0 + J])); } }
    DOIT(0, d4.x) DOIT(1, d4.y) DOIT(2, d4.z) DOIT(3, d4.w)
#undef DOIT
}

__global__ __launch_bounds__(256) void flag_kernel(const int* __restrict__ idx,
                                                   const int* __restrict__ jmap,
                                                   const int* __restrict__ countsA,
                                                   const int2* __restrict__ bktA,
                                                   int* __restrict__ flags) {
    const int j = blockIdx.x * 256 + threadIdx.x;
    if (j >= NIDX) return;
    if (jmap[idx[j]] != j + 1) return;   // dup: not the rep
    const int deg = min(countsA[j], CAP);
    for (int c = 0; c < deg; ++c)
        flags[bktA[(size_t)j * CAP + c].x] = 1;
}

__global__ __launch_bounds__(256) void compact_kernel(int* __restrict__ flags,
                                                      int* __restrict__ list,
                                                      int* __restrict__ nflag) {
    const int n = blockIdx.x * 256 + threadIdx.x;
    if (n < N_NODES && flags[n]) {
        const int s = atomicAdd(nflag, 1);
        if (s < MAXFLAG) { flags[n] = s + 1; list[s] = n; }
        else flags[n] = 0;
    }
}

// scan 2 (4 edges/thread): append flagged-dst edges into dense slot buckets
__global__ __launch_bounds__(256) void bucket_flag_kernel(const int* __restrict__ esrc,
                                                          const int* __restrict__ edst,
                                                          const float* __restrict__ ew,
                                                          const int* __restrict__ flags,
                                                          int* __restrict__ countsB,
                                                          int2* __restrict__ bktB) {
    const int e0 = (blockIdx.x * 256 + threadIdx.x) * 4;
    if (e0 >= E_NUM) return;
    const int4 d4 = *(const int4*)(edst + e0);
#define DOIT(J, DD) { const int s = flags[DD]; if (s) { \
        const int c = atomicAdd(&countsB[s - 1], 1); \
        if (c < CAP) bktB[(size_t)(s - 1) * CAP + c] = make_int2(esrc[e0 + J], __float_as_int(ew[e0 + J])); } }
    DOIT(0, d4.x) DOIT(1, d4.y) DOIT(2, d4.z) DOIT(3, d4.w)
#undef DOIT
}

// ---------------------------------------------------------------------------
// SPMM1+ReLU over compacted flagged nodes; 1 wave/node, 2 cols/lane (bf16 io)
// ---------------------------------------------------------------------------
__global__ __launch_bounds__(256) void spmm1_kernel(const ushort* __restrict__ XW0b,
                                                    const int* __restrict__ list,
                                                    const int* __restrict__ nflag,
                                                    const int* __restrict__ countsB,
                                                    const int2* __restrict__ bktB,
                                                    ushort* __restrict__ H) {
    const int lane = threadIdx.x & 63;
    const int nf = *nflag;
    const int nw = gridDim.x * 4;
    for (int wdx = blockIdx.x * 4 + (threadIdx.x >> 6); wdx < nf; wdx += nw) {
        const int n = list[wdx];
        const int deg = min(countsB[wdx], CAP);
        float a0 = 0.f, a1 = 0.f;
        int c = 0;
        for (; c + 1 < deg; c += 2) {             // unroll-2: 2 gathers in flight
            const int2 p0 = bktB[(size_t)wdx * CAP + c];
            const int2 p1 = bktB[(size_t)wdx * CAP + c + 1];
            const uint v0 = *(const uint*)(XW0b + (size_t)p0.x * HID + 2 * lane);
            const uint v1 = *(const uint*)(XW0b + (size_t)p1.x * HID + 2 * lane);
            const float w0 = __int_as_float(p0.y), w1 = __int_as_float(p1.y);
            a0 += w0 * bf2f((ushort)(v0 & 0xffffu)) + w1 * bf2f((ushort)(v1 & 0xffffu));
            a1 += w0 * bf2f((ushort)(v0 >> 16))     + w1 * bf2f((ushort)(v1 >> 16));
        }
        if (c < deg) {
            const int2 p = bktB[(size_t)wdx * CAP + c];
            const float wt = __int_as_float(p.y);
            const uint v = *(const uint*)(XW0b + (size_t)p.x * HID + 2 * lane);
            a0 += wt * bf2f((ushort)(v & 0xffffu));
            a1 += wt * bf2f((ushort)(v >> 16));
        }
        const uint o = (uint)f2bf(fmaxf(a0, 0.f)) | ((uint)f2bf(fmaxf(a1, 0.f)) << 16);
        *(uint*)(H + (size_t)n * HID + 2 * lane) = o;
    }
}

// ---------------------------------------------------------------------------
// SPMM2 (idx rows) fused with GEMM2: out[j] = (sum w*H[src]) @ W1
// ---------------------------------------------------------------------------
__global__ __launch_bounds__(64) void spmm2_kernel(const ushort* __restrict__ H,
                                                   const float* __restrict__ W1,
                                                   const int* __restrict__ idx,
                                                   const int* __restrict__ jmap,
                                                   const int* __restrict__ countsA,
                                                   const int2* __restrict__ bktA,
                                                   float* __restrict__ outp) {
    __shared__ float aggs[HID];
    const int j = blockIdx.x, lane = threadIdx.x;
    const int r = jmap[idx[j]] - 1;       // rep slot (shared by dup idx entries)
    const int deg = min(countsA[r], CAP);
    float a0 = 0.f, a1 = 0.f;
    for (int c = 0; c < deg; ++c) {
        const int2 p = bktA[(size_t)r * CAP + c];
        const float wt = __int_as_float(p.y);
        const uint v = *(const uint*)(H + (size_t)p.x * HID + 2 * lane);
        a0 += wt * bf2f((ushort)(v & 0xffffu));
        a1 += wt * bf2f((ushort)(v >> 16));
    }
    aggs[2 * lane] = a0; aggs[2 * lane + 1] = a1;
    __syncthreads();
    float s = 0.f;
#pragma unroll 8
    for (int k = 0; k < HID; ++k) s += aggs[k] * W1[k * OUT_F + lane];
    outp[(size_t)j * OUT_F + lane] = s;
}

// ---------------------------------------------------------------------------
extern "C" void kernel_launch(void* const* d_in, const int* in_sizes, int n_in,
                              void* d_out, int out_size, void* d_ws, size_t ws_size,
                              hipStream_t stream) {
    const float* x    = (const float*)d_in[0];
    const float* W0   = (const float*)d_in[1];
    const float* W1   = (const float*)d_in[2];
    const float* ew   = (const float*)d_in[3];
    const int*   esrc = (const int*)d_in[4];
    const int*   edst = (const int*)d_in[5];
    const int*   idx  = (const int*)d_in[6];
    float* outp = (float*)d_out;

    char* ws = (char*)d_ws;
    ushort* XW0b   = (ushort*)(ws);                      // 12,800,000
    ushort* H      = (ushort*)(ws + 12800000);           // 12,800,000
    ushort* W0t    = (ushort*)(ws + 25600000);           //    131,072
    int2*   bktA   = (int2*)  (ws + 25731072);           //    384,000
    int2*   bktB   = (int2*)  (ws + 26115072);           //  7,864,320
    int*    list   = (int*)   (ws + 33979392);           //     81,920
    char*   zbase  = ws + 34061312;                      // zeroed control block
    int*    countsA = (int*)(zbase);                     //      4,096
    int*    countsB = (int*)(zbase + 4096);              //     81,920
    int*    flags   = (int*)(zbase + 86016);             //    200,000
    int*    jmap    = (int*)(zbase + 286016);            //    200,000
    int*    nflag   = (int*)(zbase + 486016);            //        256
    hipMemsetAsync(zbase, 0, 486272, stream);

    prep_kernel       <<<68, 256, 0, stream>>>(W0, W0t, idx, jmap);
    bucket_idx_kernel <<<(E_NUM / 4 + 255) / 256, 256, 0, stream>>>(esrc, edst, ew, jmap, countsA, bktA);
    flag_kernel       <<<(NIDX + 255) / 256, 256, 0, stream>>>(idx, jmap, countsA, bktA, flags);
    compact_kernel    <<<(N_NODES + 255) / 256, 256, 0, stream>>>(flags, list, nflag);
    bucket_flag_kernel<<<(E_NUM / 4 + 255) / 256, 256, 0, stream>>>(esrc, edst, ew, flags, countsB, bktB);
    gemm1_direct      <<<391, 256, 0, stream>>>(x, W0t, XW0b);
    spmm1_kernel      <<<1024, 256, 0, stream>>>(XW0b, list, nflag, countsB, bktB, H);
    spmm2_kernel      <<<NIDX, 64, 0, stream>>>(H, W1, idx, jmap, countsA, bktA, outp);
}

// Round 5
// 115.503 us; speedup vs baseline: 2.0499x; 1.2872x over previous
//
#include <hip/hip_runtime.h>
#include <hip/hip_bf16.h>

#define N_NODES 50000
#define F_IN    512
#define HID     128
#define OUT_F   64
#define NIDX    1000
#define E_NUM   800000
#define CAP     48       // Poisson(16): P(deg>48) ~ 1e-11 per node
#define MAXFLAG 20480    // flagged-node capacity (expected ~13.6k)

typedef __attribute__((ext_vector_type(8))) short short8;
typedef __attribute__((ext_vector_type(4))) float f32x4;

__device__ inline ushort f2bf(float f) {
    __hip_bfloat16 h = __float2bfloat16(f);   // RNE
    return *reinterpret_cast<ushort*>(&h);
}
__device__ inline float bf2f(ushort u) {
    return __uint_as_float(((uint)u) << 16);
}
__device__ inline short8 pack8(f32x4 a, f32x4 b) {
    short8 r;
    r[0] = (short)f2bf(a[0]); r[1] = (short)f2bf(a[1]);
    r[2] = (short)f2bf(a[2]); r[3] = (short)f2bf(a[3]);
    r[4] = (short)f2bf(b[0]); r[5] = (short)f2bf(b[1]);
    r[6] = (short)f2bf(b[2]); r[7] = (short)f2bf(b[3]);
    return r;
}

// async global->LDS, 16B per lane; lds ptr must be wave-uniform (HW adds lane*16)
#define GLOAD_LDS16(g, l) __builtin_amdgcn_global_load_lds( \
    (const __attribute__((address_space(1))) unsigned int*)(g), \
    (__attribute__((address_space(3))) unsigned int*)(l), 16, 0, 0)

// ---------------------------------------------------------------------------
// prep: W0t[n][k] = bf16(W0[k][n]) via LDS transpose; jmap[idx[j]] = j+1
// ---------------------------------------------------------------------------
__global__ __launch_bounds__(256) void prep_kernel(const float* __restrict__ W0,
                                                   ushort* __restrict__ W0t,
                                                   const int* __restrict__ idx,
                                                   int* __restrict__ jmap) {
    const int b = blockIdx.x;
    if (b < 64) {   // 16 k-tiles x 4 n-tiles of 32x32
        __shared__ float tl[32][33];
        const int k0 = (b & 15) * 32, n0 = (b >> 4) * 32;
        const int tx = threadIdx.x & 31, ty = threadIdx.x >> 5;   // ty 0..7
#pragma unroll
        for (int i = 0; i < 4; ++i)
            tl[ty + i * 8][tx] = W0[(size_t)(k0 + ty + i * 8) * HID + n0 + tx];
        __syncthreads();
#pragma unroll
        for (int i = 0; i < 4; ++i) {
            const int n = ty + i * 8;
            W0t[(size_t)(n0 + n) * F_IN + k0 + tx] = f2bf(tl[tx][n]);
        }
    } else {        // blocks 64..67: mark idx reps
        const int j = (b - 64) * 256 + threadIdx.x;
        if (j < NIDX) jmap[idx[j]] = j + 1;
    }
}

// ---------------------------------------------------------------------------
// GEMM1: XW0b = bf16(x @ W0). m97-style global_load_lds staging, 2-phase,
// BM=64, BK=32, 4 waves (2x2; wave tile 32x64). A staged fp32 (cvt on read),
// B staged bf16. Linear LDS dest + inverse-swizzled SOURCE + swizzled READ
// (rule 21): A chunk ^= row&7, B chunk ^= (n>>1)&3  -> 2-way (free) ds_reads.
// ---------------------------------------------------------------------------
__global__ __launch_bounds__(256, 4) void gemm1_mfma(const float* __restrict__ x,
                                                     const ushort* __restrict__ W0t,
                                                     ushort* __restrict__ XW0b) {
    __shared__ __align__(16) char smem[32768];  // A0|A1|B0|B1 (8KB each); epilogue overlay

    const int t = threadIdx.x;
    const int w = t >> 6, lane = t & 63;
    const int wr = w >> 1, wc = w & 1;
    const int lr = lane & 15, lk = lane >> 4;
    const int m0 = blockIdx.x * 64;

    f32x4 acc[2][4] = {};

    auto stage = [&](int buf, int k0) {
        char* lA = smem + buf * 8192;
        char* lB = smem + 16384 + buf * 8192;
#pragma unroll
        for (int i = 0; i < 2; ++i) {
            {   // A: 64 rows x 32 f32 = 512 chunks of 16B
                const int o = i * 256 + t;
                const int row = o >> 3, c = o & 7;
                int grow = m0 + row; if (grow > N_NODES - 1) grow = N_NODES - 1;
                const float* g = x + (size_t)grow * F_IN + k0 + ((c ^ (row & 7)) << 2);
                GLOAD_LDS16(g, lA + (i * 256 + w * 64) * 16);
            }
            {   // B: 128 rows x 32 bf16 = 512 chunks of 16B
                const int o = i * 256 + t;
                const int row = o >> 2, c = o & 3;
                const ushort* g = W0t + (size_t)row * F_IN + k0 + ((c ^ ((row >> 1) & 3)) << 3);
                GLOAD_LDS16(g, lB + (i * 256 + w * 64) * 16);
            }
        }
    };

    stage(0, 0);
    __syncthreads();
    int cur = 0;
    for (int kt = 0; kt < 16; ++kt) {
        if (kt < 15) stage(cur ^ 1, (kt + 1) * 32);   // issue before compute (T3 2-phase)
        const float*  Af = (const float*)(smem + cur * 8192);
        const ushort* Bf = (const ushort*)(smem + 16384 + cur * 8192);
        short8 a[2], b[4];
#pragma unroll
        for (int mi = 0; mi < 2; ++mi) {
            const int R = wr * 32 + mi * 16 + lr;
            const float* ar = Af + R * 32;
            const f32x4 lo = *(const f32x4*)(ar + (((2 * lk + 0) ^ (R & 7)) << 2));
            const f32x4 hi = *(const f32x4*)(ar + (((2 * lk + 1) ^ (R & 7)) << 2));
            a[mi] = pack8(lo, hi);
        }
#pragma unroll
        for (int ni = 0; ni < 4; ++ni) {
            const int n = wc * 64 + ni * 16 + lr;
            b[ni] = *(const short8*)(Bf + n * 32 + ((lk ^ ((n >> 1) & 3)) << 3));
        }
#pragma unroll
        for (int mi = 0; mi < 2; ++mi)
#pragma unroll
            for (int ni = 0; ni < 4; ++ni)
                acc[mi][ni] = __builtin_amdgcn_mfma_f32_16x16x32_bf16(
                    a[mi], b[ni], acc[mi][ni], 0, 0, 0);
        __syncthreads();   // drains stage loads (vmcnt0) + guards buffer swap
        cur ^= 1;
    }

    // epilogue: acc (col=lr, row=lk*4+r) -> LDS transpose -> coalesced 16B stores
    float* ep = (float*)smem + w * (16 * 68);
#pragma unroll
    for (int mi = 0; mi < 2; ++mi) {
        __syncthreads();
#pragma unroll
        for (int ni = 0; ni < 4; ++ni)
#pragma unroll
            for (int r = 0; r < 4; ++r)
                ep[(lk * 4 + r) * 68 + ni * 16 + lr] = acc[mi][ni][r];
        __syncthreads();
        const int rr = lane >> 2, cq = lane & 3;
        const int grow = m0 + wr * 32 + mi * 16 + rr;
        alignas(16) float vv[16];
#pragma unroll
        for (int j = 0; j < 4; ++j)
            *(f32x4*)&vv[j * 4] = *(const f32x4*)&ep[rr * 68 + cq * 16 + j * 4];
        if (grow < N_NODES) {
            alignas(16) ushort us[16];
#pragma unroll
            for (int jj = 0; jj < 16; ++jj) us[jj] = f2bf(vv[jj]);
            ushort* orow = XW0b + (size_t)grow * HID + wc * 64 + cq * 16;
            *(uint4*)(orow)     = *(const uint4*)&us[0];
            *(uint4*)(orow + 8) = *(const uint4*)&us[8];
        }
    }
}

// ---------------------------------------------------------------------------
// scan 1 (4 edges/thread): append idx-dst edges into dense 1000-slot buckets
// AND flag their srcs (fused; removes the separate flag kernel)
// ---------------------------------------------------------------------------
__global__ __launch_bounds__(256) void bucket_idx_kernel(const int* __restrict__ esrc,
                                                         const int* __restrict__ edst,
                                                         const float* __restrict__ ew,
                                                         const int* __restrict__ jmap,
                                                         int* __restrict__ countsA,
                                                         int2* __restrict__ bktA,
                                                         int* __restrict__ flags) {
    const int e0 = (blockIdx.x * 256 + threadIdx.x) * 4;
    if (e0 >= E_NUM) return;
    const int4 d4 = *(const int4*)(edst + e0);
#define DOIT(J, DD) { const int rep = jmap[DD]; if (rep) { \
        const int r = rep - 1; const int c = atomicAdd(&countsA[r], 1); \
        const int s = esrc[e0 + J]; \
        if (c < CAP) bktA[(size_t)r * CAP + c] = make_int2(s, __float_as_int(ew[e0 + J])); \
        flags[s] = 1; } }
    DOIT(0, d4.x) DOIT(1, d4.y) DOIT(2, d4.z) DOIT(3, d4.w)
#undef DOIT
}

__global__ __launch_bounds__(256) void compact_kernel(int* __restrict__ flags,
                                                      int* __restrict__ list,
                                                      int* __restrict__ nflag) {
    const int n = blockIdx.x * 256 + threadIdx.x;
    if (n < N_NODES && flags[n]) {
        const int s = atomicAdd(nflag, 1);
        if (s < MAXFLAG) { flags[n] = s + 1; list[s] = n; }
        else flags[n] = 0;
    }
}

// scan 2 (4 edges/thread): append flagged-dst edges into dense slot buckets
__global__ __launch_bounds__(256) void bucket_flag_kernel(const int* __restrict__ esrc,
                                                          const int* __restrict__ edst,
                                                          const float* __restrict__ ew,
                                                          const int* __restrict__ flags,
                                                          int* __restrict__ countsB,
                                                          int2* __restrict__ bktB) {
    const int e0 = (blockIdx.x * 256 + threadIdx.x) * 4;
    if (e0 >= E_NUM) return;
    const int4 d4 = *(const int4*)(edst + e0);
#define DOIT(J, DD) { const int s = flags[DD]; if (s) { \
        const int c = atomicAdd(&countsB[s - 1], 1); \
        if (c < CAP) bktB[(size_t)(s - 1) * CAP + c] = make_int2(esrc[e0 + J], __float_as_int(ew[e0 + J])); } }
    DOIT(0, d4.x) DOIT(1, d4.y) DOIT(2, d4.z) DOIT(3, d4.w)
#undef DOIT
}

// ---------------------------------------------------------------------------
// SPMM1+ReLU over compacted flagged nodes; 1 wave/node, 2 cols/lane (bf16 io)
// ---------------------------------------------------------------------------
__global__ __launch_bounds__(256) void spmm1_kernel(const ushort* __restrict__ XW0b,
                                                    const int* __restrict__ list,
                                                    const int* __restrict__ nflag,
                                                    const int* __restrict__ countsB,
                                                    const int2* __restrict__ bktB,
                                                    ushort* __restrict__ H) {
    const int lane = threadIdx.x & 63;
    const int nf = *nflag;
    const int nw = gridDim.x * 4;
    for (int wdx = blockIdx.x * 4 + (threadIdx.x >> 6); wdx < nf; wdx += nw) {
        const int n = list[wdx];
        const int deg = min(countsB[wdx], CAP);
        float a0 = 0.f, a1 = 0.f;
        int c = 0;
        for (; c + 1 < deg; c += 2) {             // 2 gathers in flight
            const int2 p0 = bktB[(size_t)wdx * CAP + c];
            const int2 p1 = bktB[(size_t)wdx * CAP + c + 1];
            const uint v0 = *(const uint*)(XW0b + (size_t)p0.x * HID + 2 * lane);
            const uint v1 = *(const uint*)(XW0b + (size_t)p1.x * HID + 2 * lane);
            const float w0 = __int_as_float(p0.y), w1 = __int_as_float(p1.y);
            a0 += w0 * bf2f((ushort)(v0 & 0xffffu)) + w1 * bf2f((ushort)(v1 & 0xffffu));
            a1 += w0 * bf2f((ushort)(v0 >> 16))     + w1 * bf2f((ushort)(v1 >> 16));
        }
        if (c < deg) {
            const int2 p = bktB[(size_t)wdx * CAP + c];
            const float wt = __int_as_float(p.y);
            const uint v = *(const uint*)(XW0b + (size_t)p.x * HID + 2 * lane);
            a0 += wt * bf2f((ushort)(v & 0xffffu));
            a1 += wt * bf2f((ushort)(v >> 16));
        }
        const uint o = (uint)f2bf(fmaxf(a0, 0.f)) | ((uint)f2bf(fmaxf(a1, 0.f)) << 16);
        *(uint*)(H + (size_t)n * HID + 2 * lane) = o;
    }
}

// ---------------------------------------------------------------------------
// SPMM2 (idx rows) fused with GEMM2: out[j] = (sum w*H[src]) @ W1
// ---------------------------------------------------------------------------
__global__ __launch_bounds__(64) void spmm2_kernel(const ushort* __restrict__ H,
                                                   const float* __restrict__ W1,
                                                   const int* __restrict__ idx,
                                                   const int* __restrict__ jmap,
                                                   const int* __restrict__ countsA,
                                                   const int2* __restrict__ bktA,
                                                   float* __restrict__ outp) {
    __shared__ float aggs[HID];
    const int j = blockIdx.x, lane = threadIdx.x;
    const int r = jmap[idx[j]] - 1;       // rep slot (shared by dup idx entries)
    const int deg = min(countsA[r], CAP);
    float a0 = 0.f, a1 = 0.f;
    for (int c = 0; c < deg; ++c) {
        const int2 p = bktA[(size_t)r * CAP + c];
        const float wt = __int_as_float(p.y);
        const uint v = *(const uint*)(H + (size_t)p.x * HID + 2 * lane);
        a0 += wt * bf2f((ushort)(v & 0xffffu));
        a1 += wt * bf2f((ushort)(v >> 16));
    }
    aggs[2 * lane] = a0; aggs[2 * lane + 1] = a1;
    __syncthreads();
    float s = 0.f;
#pragma unroll 8
    for (int k = 0; k < HID; ++k) s += aggs[k] * W1[k * OUT_F + lane];
    outp[(size_t)j * OUT_F + lane] = s;
}

// ---------------------------------------------------------------------------
extern "C" void kernel_launch(void* const* d_in, const int* in_sizes, int n_in,
                              void* d_out, int out_size, void* d_ws, size_t ws_size,
                              hipStream_t stream) {
    const float* x    = (const float*)d_in[0];
    const float* W0   = (const float*)d_in[1];
    const float* W1   = (const float*)d_in[2];
    const float* ew   = (const float*)d_in[3];
    const int*   esrc = (const int*)d_in[4];
    const int*   edst = (const int*)d_in[5];
    const int*   idx  = (const int*)d_in[6];
    float* outp = (float*)d_out;

    char* ws = (char*)d_ws;
    ushort* XW0b   = (ushort*)(ws);                      // 12,800,000
    ushort* H      = (ushort*)(ws + 12800000);           // 12,800,000
    ushort* W0t    = (ushort*)(ws + 25600000);           //    131,072
    int2*   bktA   = (int2*)  (ws + 25731072);           //    384,000
    int2*   bktB   = (int2*)  (ws + 26115072);           //  7,864,320
    int*    list   = (int*)   (ws + 33979392);           //     81,920
    char*   zbase  = ws + 34061312;                      // zeroed control block
    int*    countsA = (int*)(zbase);                     //      4,096
    int*    countsB = (int*)(zbase + 4096);              //     81,920
    int*    flags   = (int*)(zbase + 86016);             //    200,000
    int*    jmap    = (int*)(zbase + 286016);            //    200,000
    int*    nflag   = (int*)(zbase + 486016);            //        256
    hipMemsetAsync(zbase, 0, 486272, stream);

    prep_kernel       <<<68, 256, 0, stream>>>(W0, W0t, idx, jmap);
    bucket_idx_kernel <<<(E_NUM / 4 + 255) / 256, 256, 0, stream>>>(esrc, edst, ew, jmap, countsA, bktA, flags);
    compact_kernel    <<<(N_NODES + 255) / 256, 256, 0, stream>>>(flags, list, nflag);
    bucket_flag_kernel<<<(E_NUM / 4 + 255) / 256, 256, 0, stream>>>(esrc, edst, ew, flags, countsB, bktB);
    gemm1_mfma        <<<(N_NODES + 63) / 64, 256, 0, stream>>>(x, W0t, XW0b);
    spmm1_kernel      <<<1024, 256, 0, stream>>>(XW0b, list, nflag, countsB, bktB, H);
    spmm2_kernel      <<<NIDX, 64, 0, stream>>>(H, W1, idx, jmap, countsA, bktA, outp);
}

// Round 6
// 106.945 us; speedup vs baseline: 2.2140x; 1.0800x over previous
//
#include <hip/hip_runtime.h>
#include <hip/hip_bf16.h>

#define N_NODES 50000
#define F_IN    512
#define HID     128
#define OUT_F   64
#define NIDX    1000
#define E_NUM   800000
#define CAP     48       // Poisson(16): P(deg>48) ~ 1e-11 per node
#define MAXFLAG 20480    // flagged-node capacity (expected ~13.6k)

typedef __attribute__((ext_vector_type(8))) short short8;
typedef __attribute__((ext_vector_type(4))) float f32x4;

__device__ inline ushort f2bf(float f) {
    __hip_bfloat16 h = __float2bfloat16(f);   // RNE
    return *reinterpret_cast<ushort*>(&h);
}
__device__ inline float bf2f(ushort u) {
    return __uint_as_float(((uint)u) << 16);
}
__device__ inline short8 pack8(f32x4 a, f32x4 b) {
    short8 r;
    r[0] = (short)f2bf(a[0]); r[1] = (short)f2bf(a[1]);
    r[2] = (short)f2bf(a[2]); r[3] = (short)f2bf(a[3]);
    r[4] = (short)f2bf(b[0]); r[5] = (short)f2bf(b[1]);
    r[6] = (short)f2bf(b[2]); r[7] = (short)f2bf(b[3]);
    return r;
}

// async global->LDS, 16B per lane; lds ptr wave-uniform (HW adds lane*16)
#define GLOAD_LDS16(g, l) __builtin_amdgcn_global_load_lds( \
    (const __attribute__((address_space(1))) unsigned int*)(g), \
    (__attribute__((address_space(3))) unsigned int*)(l), 16, 0, 0)

// ---------------------------------------------------------------------------
// prep: W0t[n][k] = bf16(W0[k][n]) via LDS transpose; jmap[idx[j]] = j+1
// ---------------------------------------------------------------------------
__global__ __launch_bounds__(256) void prep_kernel(const float* __restrict__ W0,
                                                   ushort* __restrict__ W0t,
                                                   const int* __restrict__ idx,
                                                   ushort* __restrict__ jmap) {
    const int b = blockIdx.x;
    if (b < 64) {   // 16 k-tiles x 4 n-tiles of 32x32
        __shared__ float tl[32][33];
        const int k0 = (b & 15) * 32, n0 = (b >> 4) * 32;
        const int tx = threadIdx.x & 31, ty = threadIdx.x >> 5;   // ty 0..7
#pragma unroll
        for (int i = 0; i < 4; ++i)
            tl[ty + i * 8][tx] = W0[(size_t)(k0 + ty + i * 8) * HID + n0 + tx];
        __syncthreads();
#pragma unroll
        for (int i = 0; i < 4; ++i) {
            const int n = ty + i * 8;
            W0t[(size_t)(n0 + n) * F_IN + k0 + tx] = f2bf(tl[tx][n]);
        }
    } else {        // blocks 64..67: mark idx reps (dup winner arbitrary; output-invariant)
        const int j = (b - 64) * 256 + threadIdx.x;
        if (j < NIDX) jmap[idx[j]] = (ushort)(j + 1);
    }
}

// ---------------------------------------------------------------------------
// GEMM1: XW0b = bf16(x @ W0). global_load_lds staging, counted-vmcnt pipeline
// (T3+T4): 2 tiles in flight, vmcnt(4) at iter top, NO vmcnt(0) drain in loop.
// BM=64, BK=32, 4 waves (2x2; wave tile 32x64). A fp32 (cvt on read), B bf16.
// Addressing/swizzle identical to the R5-verified kernel (absmax 0.25).
// ---------------------------------------------------------------------------
__global__ __launch_bounds__(256, 4) void gemm1_mfma(const float* __restrict__ x,
                                                     const ushort* __restrict__ W0t,
                                                     ushort* __restrict__ XW0b) {
    __shared__ __align__(16) char smem[32768];  // A0|A1|B0|B1 (8KB each); epilogue overlay

    const int t = threadIdx.x;
    const int w = t >> 6, lane = t & 63;
    const int wr = w >> 1, wc = w & 1;
    const int lr = lane & 15, lk = lane >> 4;
    const int m0 = blockIdx.x * 64;

    f32x4 acc[2][4] = {};

    auto stage = [&](int buf, int k0) {
        char* lA = smem + buf * 8192;
        char* lB = smem + 16384 + buf * 8192;
#pragma unroll
        for (int i = 0; i < 2; ++i) {
            {   // A: 64 rows x 32 f32 = 512 chunks of 16B
                const int o = i * 256 + t;
                const int row = o >> 3, c = o & 7;
                int grow = m0 + row; if (grow > N_NODES - 1) grow = N_NODES - 1;
                const float* g = x + (size_t)grow * F_IN + k0 + ((c ^ (row & 7)) << 2);
                GLOAD_LDS16(g, lA + (i * 256 + w * 64) * 16);
            }
            {   // B: 128 rows x 32 bf16 = 512 chunks of 16B
                const int o = i * 256 + t;
                const int row = o >> 2, c = o & 3;
                const ushort* g = W0t + (size_t)row * F_IN + k0 + ((c ^ ((row >> 1) & 3)) << 3);
                GLOAD_LDS16(g, lB + (i * 256 + w * 64) * 16);
            }
        }
    };

    stage(0, 0);
    stage(1, 32);            // 8 loads/thread outstanding
#pragma unroll
    for (int kt = 0; kt < 16; ++kt) {
        if (kt < 15) asm volatile("s_waitcnt vmcnt(4)" ::: "memory");  // tile kt landed
        else         asm volatile("s_waitcnt vmcnt(0)" ::: "memory");
        __builtin_amdgcn_s_barrier();            // all waves' tile-kt chunks visible

        const int cur = kt & 1;
        const float*  Af = (const float*)(smem + cur * 8192);
        const ushort* Bf = (const ushort*)(smem + 16384 + cur * 8192);
        short8 a[2], b[4];
#pragma unroll
        for (int mi = 0; mi < 2; ++mi) {
            const int R = wr * 32 + mi * 16 + lr;
            const float* ar = Af + R * 32;
            const f32x4 lo = *(const f32x4*)(ar + (((2 * lk + 0) ^ (R & 7)) << 2));
            const f32x4 hi = *(const f32x4*)(ar + (((2 * lk + 1) ^ (R & 7)) << 2));
            a[mi] = pack8(lo, hi);
        }
#pragma unroll
        for (int ni = 0; ni < 4; ++ni) {
            const int n = wc * 64 + ni * 16 + lr;
            b[ni] = *(const short8*)(Bf + n * 32 + ((lk ^ ((n >> 1) & 3)) << 3));
        }
        asm volatile("s_waitcnt lgkmcnt(0)" ::: "memory");   // my frag reads done
        __builtin_amdgcn_s_barrier();            // everyone's reads done -> buf free

        if (kt < 14) stage(cur, (kt + 2) * 32);  // refill freed buffer (issue early)

#pragma unroll
        for (int mi = 0; mi < 2; ++mi)
#pragma unroll
            for (int ni = 0; ni < 4; ++ni)
                acc[mi][ni] = __builtin_amdgcn_mfma_f32_16x16x32_bf16(
                    a[mi], b[ni], acc[mi][ni], 0, 0, 0);
    }
    __syncthreads();

    // epilogue: acc (col=lr, row=lk*4+r) -> LDS transpose -> coalesced 16B stores
    float* ep = (float*)smem + w * (16 * 68);
#pragma unroll
    for (int mi = 0; mi < 2; ++mi) {
        __syncthreads();
#pragma unroll
        for (int ni = 0; ni < 4; ++ni)
#pragma unroll
            for (int r = 0; r < 4; ++r)
                ep[(lk * 4 + r) * 68 + ni * 16 + lr] = acc[mi][ni][r];
        __syncthreads();
        const int rr = lane >> 2, cq = lane & 3;
        const int grow = m0 + wr * 32 + mi * 16 + rr;
        alignas(16) float vv[16];
#pragma unroll
        for (int j = 0; j < 4; ++j)
            *(f32x4*)&vv[j * 4] = *(const f32x4*)&ep[rr * 68 + cq * 16 + j * 4];
        if (grow < N_NODES) {
            alignas(16) ushort us[16];
#pragma unroll
            for (int jj = 0; jj < 16; ++jj) us[jj] = f2bf(vv[jj]);
            ushort* orow = XW0b + (size_t)grow * HID + wc * 64 + cq * 16;
            *(uint4*)(orow)     = *(const uint4*)&us[0];
            *(uint4*)(orow + 8) = *(const uint4*)&us[8];
        }
    }
}

// ---------------------------------------------------------------------------
// scan 1 (4 edges/thread, streamed esrc/ew): idx-dst edges -> bktA + flag srcs
// ---------------------------------------------------------------------------
__global__ __launch_bounds__(256) void bucket_idx_kernel(const int* __restrict__ esrc,
                                                         const int* __restrict__ edst,
                                                         const float* __restrict__ ew,
                                                         const ushort* __restrict__ jmap,
                                                         int* __restrict__ countsA,
                                                         int2* __restrict__ bktA,
                                                         ushort* __restrict__ flags) {
    const int e0 = (blockIdx.x * 256 + threadIdx.x) * 4;
    if (e0 >= E_NUM) return;
    const int4   d4 = *(const int4*)(edst + e0);
    const int4   s4 = *(const int4*)(esrc + e0);
    const float4 w4 = *(const float4*)(ew + e0);
#define DOIT(DD, SS, WW) { const int rep = jmap[DD]; if (rep) { \
        const int r = rep - 1; const int c = atomicAdd(&countsA[r], 1); \
        if (c < CAP) bktA[(size_t)r * CAP + c] = make_int2(SS, __float_as_int(WW)); \
        flags[SS] = 1; } }
    DOIT(d4.x, s4.x, w4.x) DOIT(d4.y, s4.y, w4.y)
    DOIT(d4.z, s4.z, w4.z) DOIT(d4.w, s4.w, w4.w)
#undef DOIT
}

__global__ __launch_bounds__(256) void compact_kernel(ushort* __restrict__ flags,
                                                      int* __restrict__ list,
                                                      int* __restrict__ nflag) {
    const int n = blockIdx.x * 256 + threadIdx.x;
    if (n < N_NODES && flags[n]) {
        const int s = atomicAdd(nflag, 1);
        if (s < MAXFLAG) { flags[n] = (ushort)(s + 1); list[s] = n; }
        else flags[n] = 0;
    }
}

// scan 2 (4 edges/thread, streamed): flagged-dst edges -> dense slot buckets
__global__ __launch_bounds__(256) void bucket_flag_kernel(const int* __restrict__ esrc,
                                                          const int* __restrict__ edst,
                                                          const float* __restrict__ ew,
                                                          const ushort* __restrict__ flags,
                                                          int* __restrict__ countsB,
                                                          int2* __restrict__ bktB) {
    const int e0 = (blockIdx.x * 256 + threadIdx.x) * 4;
    if (e0 >= E_NUM) return;
    const int4   d4 = *(const int4*)(edst + e0);
    const int4   s4 = *(const int4*)(esrc + e0);
    const float4 w4 = *(const float4*)(ew + e0);
#define DOIT(DD, SS, WW) { const int s = flags[DD]; if (s) { \
        const int c = atomicAdd(&countsB[s - 1], 1); \
        if (c < CAP) bktB[(size_t)(s - 1) * CAP + c] = make_int2(SS, __float_as_int(WW)); } }
    DOIT(d4.x, s4.x, w4.x) DOIT(d4.y, s4.y, w4.y)
    DOIT(d4.z, s4.z, w4.z) DOIT(d4.w, s4.w, w4.w)
#undef DOIT
}

// ---------------------------------------------------------------------------
// SPMM1+ReLU over compacted flagged nodes; 1 wave/node, 2 cols/lane, unroll-4
// ---------------------------------------------------------------------------
__global__ __launch_bounds__(256) void spmm1_kernel(const ushort* __restrict__ XW0b,
                                                    const int* __restrict__ list,
                                                    const int* __restrict__ nflag,
                                                    const int* __restrict__ countsB,
                                                    const int2* __restrict__ bktB,
                                                    ushort* __restrict__ H) {
    const int lane = threadIdx.x & 63;
    const int nf = *nflag;
    const int nw = gridDim.x * 4;
    for (int wdx = blockIdx.x * 4 + (threadIdx.x >> 6); wdx < nf; wdx += nw) {
        const int n = list[wdx];
        const int deg = min(countsB[wdx], CAP);
        float a0 = 0.f, a1 = 0.f;
        int c = 0;
        for (; c + 3 < deg; c += 4) {             // 4 gathers in flight
            const int2 p0 = bktB[(size_t)wdx * CAP + c];
            const int2 p1 = bktB[(size_t)wdx * CAP + c + 1];
            const int2 p2 = bktB[(size_t)wdx * CAP + c + 2];
            const int2 p3 = bktB[(size_t)wdx * CAP + c + 3];
            const uint v0 = *(const uint*)(XW0b + (size_t)p0.x * HID + 2 * lane);
            const uint v1 = *(const uint*)(XW0b + (size_t)p1.x * HID + 2 * lane);
            const uint v2 = *(const uint*)(XW0b + (size_t)p2.x * HID + 2 * lane);
            const uint v3 = *(const uint*)(XW0b + (size_t)p3.x * HID + 2 * lane);
            const float w0 = __int_as_float(p0.y), w1 = __int_as_float(p1.y);
            const float w2 = __int_as_float(p2.y), w3 = __int_as_float(p3.y);
            a0 += w0 * bf2f((ushort)(v0 & 0xffffu)) + w1 * bf2f((ushort)(v1 & 0xffffu))
                + w2 * bf2f((ushort)(v2 & 0xffffu)) + w3 * bf2f((ushort)(v3 & 0xffffu));
            a1 += w0 * bf2f((ushort)(v0 >> 16))     + w1 * bf2f((ushort)(v1 >> 16))
                + w2 * bf2f((ushort)(v2 >> 16))     + w3 * bf2f((ushort)(v3 >> 16));
        }
        for (; c < deg; ++c) {
            const int2 p = bktB[(size_t)wdx * CAP + c];
            const float wt = __int_as_float(p.y);
            const uint v = *(const uint*)(XW0b + (size_t)p.x * HID + 2 * lane);
            a0 += wt * bf2f((ushort)(v & 0xffffu));
            a1 += wt * bf2f((ushort)(v >> 16));
        }
        const uint o = (uint)f2bf(fmaxf(a0, 0.f)) | ((uint)f2bf(fmaxf(a1, 0.f)) << 16);
        *(uint*)(H + (size_t)n * HID + 2 * lane) = o;
    }
}

// ---------------------------------------------------------------------------
// SPMM2 (idx rows) fused with GEMM2: out[j] = (sum w*H[src]) @ W1
// ---------------------------------------------------------------------------
__global__ __launch_bounds__(64) void spmm2_kernel(const ushort* __restrict__ H,
                                                   const float* __restrict__ W1,
                                                   const int* __restrict__ idx,
                                                   const ushort* __restrict__ jmap,
                                                   const int* __restrict__ countsA,
                                                   const int2* __restrict__ bktA,
                                                   float* __restrict__ outp) {
    __shared__ float aggs[HID];
    const int j = blockIdx.x, lane = threadIdx.x;
    const int r = (int)jmap[idx[j]] - 1;  // rep slot (shared by dup idx entries)
    const int deg = min(countsA[r], CAP);
    float a0 = 0.f, a1 = 0.f;
    for (int c = 0; c < deg; ++c) {
        const int2 p = bktA[(size_t)r * CAP + c];
        const float wt = __int_as_float(p.y);
        const uint v = *(const uint*)(H + (size_t)p.x * HID + 2 * lane);
        a0 += wt * bf2f((ushort)(v & 0xffffu));
        a1 += wt * bf2f((ushort)(v >> 16));
    }
    aggs[2 * lane] = a0; aggs[2 * lane + 1] = a1;
    __syncthreads();
    float s = 0.f;
#pragma unroll 8
    for (int k = 0; k < HID; ++k) s += aggs[k] * W1[k * OUT_F + lane];
    outp[(size_t)j * OUT_F + lane] = s;
}

// ---------------------------------------------------------------------------
extern "C" void kernel_launch(void* const* d_in, const int* in_sizes, int n_in,
                              void* d_out, int out_size, void* d_ws, size_t ws_size,
                              hipStream_t stream) {
    const float* x    = (const float*)d_in[0];
    const float* W0   = (const float*)d_in[1];
    const float* W1   = (const float*)d_in[2];
    const float* ew   = (const float*)d_in[3];
    const int*   esrc = (const int*)d_in[4];
    const int*   edst = (const int*)d_in[5];
    const int*   idx  = (const int*)d_in[6];
    float* outp = (float*)d_out;

    char* ws = (char*)d_ws;
    ushort* XW0b   = (ushort*)(ws);                      // 12,800,000
    ushort* H      = (ushort*)(ws + 12800000);           // 12,800,000
    ushort* W0t    = (ushort*)(ws + 25600000);           //    131,072
    int2*   bktA   = (int2*)  (ws + 25731072);           //    384,000
    int2*   bktB   = (int2*)  (ws + 26115072);           //  7,864,320
    int*    list   = (int*)   (ws + 33979392);           //     81,920
    char*   zbase  = ws + 34061312;                      // zeroed control block
    int*    countsA = (int*)   (zbase);                  //      4,096
    int*    countsB = (int*)   (zbase + 4096);           //     81,920
    ushort* flags   = (ushort*)(zbase + 86016);          //    100,352
    ushort* jmap    = (ushort*)(zbase + 186368);         //    100,352
    int*    nflag   = (int*)   (zbase + 286720);         //        256
    hipMemsetAsync(zbase, 0, 286976, stream);

    prep_kernel       <<<68, 256, 0, stream>>>(W0, W0t, idx, jmap);
    bucket_idx_kernel <<<(E_NUM / 4 + 255) / 256, 256, 0, stream>>>(esrc, edst, ew, jmap, countsA, bktA, flags);
    compact_kernel    <<<(N_NODES + 255) / 256, 256, 0, stream>>>(flags, list, nflag);
    bucket_flag_kernel<<<(E_NUM / 4 + 255) / 256, 256, 0, stream>>>(esrc, edst, ew, flags, countsB, bktB);
    gemm1_mfma        <<<(N_NODES + 63) / 64, 256, 0, stream>>>(x, W0t, XW0b);
    spmm1_kernel      <<<1024, 256, 0, stream>>>(XW0b, list, nflag, countsB, bktB, H);
    spmm2_kernel      <<<NIDX, 64, 0, stream>>>(H, W1, idx, jmap, countsA, bktA, outp);
}

// Round 7
// 92.874 us; speedup vs baseline: 2.5494x; 1.1515x over previous
//
#include <hip/hip_runtime.h>
#include <hip/hip_bf16.h>

#define N_NODES 50000
#define F_IN    512
#define HID     128
#define OUT_F   64
#define NIDX    1000
#define E_NUM   800000
#define CAP     48       // Poisson(16): P(deg>48) ~ 1e-11 per node
#define MAXFLAG 20480    // flagged-node capacity (expected ~13.6k)
#define NSCAN2  196      // scan2 blocks inside the fused dispatch

typedef __attribute__((ext_vector_type(8))) short short8;
typedef __attribute__((ext_vector_type(4))) float f32x4;

__device__ inline ushort f2bf(float f) {
    __hip_bfloat16 h = __float2bfloat16(f);   // RNE
    return *reinterpret_cast<ushort*>(&h);
}
__device__ inline float bf2f(ushort u) {
    return __uint_as_float(((uint)u) << 16);
}
__device__ inline short8 pack8(f32x4 a, f32x4 b) {
    short8 r;
    r[0] = (short)f2bf(a[0]); r[1] = (short)f2bf(a[1]);
    r[2] = (short)f2bf(a[2]); r[3] = (short)f2bf(a[3]);
    r[4] = (short)f2bf(b[0]); r[5] = (short)f2bf(b[1]);
    r[6] = (short)f2bf(b[2]); r[7] = (short)f2bf(b[3]);
    return r;
}

// async global->LDS, 16B per lane; lds ptr wave-uniform (HW adds lane*16)
#define GLOAD_LDS16(g, l) __builtin_amdgcn_global_load_lds( \
    (const __attribute__((address_space(1))) unsigned int*)(g), \
    (__attribute__((address_space(3))) unsigned int*)(l), 16, 0, 0)

// ---------------------------------------------------------------------------
// prep: W0t[n][k] = bf16(W0[k][n]) via LDS transpose; jmap[idx[j]] = j+1
// ---------------------------------------------------------------------------
__global__ __launch_bounds__(256) void prep_kernel(const float* __restrict__ W0,
                                                   ushort* __restrict__ W0t,
                                                   const int* __restrict__ idx,
                                                   ushort* __restrict__ jmap) {
    const int b = blockIdx.x;
    if (b < 64) {   // 16 k-tiles x 4 n-tiles of 32x32
        __shared__ float tl[32][33];
        const int k0 = (b & 15) * 32, n0 = (b >> 4) * 32;
        const int tx = threadIdx.x & 31, ty = threadIdx.x >> 5;   // ty 0..7
#pragma unroll
        for (int i = 0; i < 4; ++i)
            tl[ty + i * 8][tx] = W0[(size_t)(k0 + ty + i * 8) * HID + n0 + tx];
        __syncthreads();
#pragma unroll
        for (int i = 0; i < 4; ++i) {
            const int n = ty + i * 8;
            W0t[(size_t)(n0 + n) * F_IN + k0 + tx] = f2bf(tl[tx][n]);
        }
    } else {        // blocks 64..67: mark idx reps (dup winner arbitrary; output-invariant)
        const int j = (b - 64) * 256 + threadIdx.x;
        if (j < NIDX) jmap[idx[j]] = (ushort)(j + 1);
    }
}

// ---------------------------------------------------------------------------
// FUSED dispatch: blocks [0,NSCAN2) run scan2 (flagged-dst edges -> bktB);
// blocks [NSCAN2, NSCAN2+782) run GEMM1. Independent jobs, one launch:
// scan2's time hides entirely under the gemm.
//
// GEMM1: XW0b = bf16(x @ W0); global_load_lds staging, DEPTH-3 counted-vmcnt
// pipeline (3 LDS buffers, vmcnt(8) steady state), BM=64, BK=32, 4 waves
// (2x2; wave tile 32x64). Addressing/swizzle identical to R5/R6 verified.
// ---------------------------------------------------------------------------
__global__ __launch_bounds__(256, 3) void fused_gemm_scan2(
        const float* __restrict__ x, const ushort* __restrict__ W0t,
        ushort* __restrict__ XW0b,
        const int* __restrict__ esrc, const int* __restrict__ edst,
        const float* __restrict__ ew, const ushort* __restrict__ flags,
        int* __restrict__ countsB, int2* __restrict__ bktB) {
    __shared__ __align__(16) char smem[49152];   // A0|A1|A2 (24KB) | B0|B1|B2 (24KB)

    if (blockIdx.x < NSCAN2) {
        // ---- scan2: grid-strided over 200k edge-quads ----
        const int tid = blockIdx.x * 256 + threadIdx.x;     // 0..50175
        for (int q = tid; q < E_NUM / 4; q += NSCAN2 * 256) {
            const int e0 = q * 4;
            const int4   d4 = *(const int4*)(edst + e0);
            const int4   s4 = *(const int4*)(esrc + e0);
            const float4 w4 = *(const float4*)(ew + e0);
#define DOIT(DD, SS, WW) { const int s = flags[DD]; if (s) { \
        const int c = atomicAdd(&countsB[s - 1], 1); \
        if (c < CAP) bktB[(size_t)(s - 1) * CAP + c] = make_int2(SS, __float_as_int(WW)); } }
            DOIT(d4.x, s4.x, w4.x) DOIT(d4.y, s4.y, w4.y)
            DOIT(d4.z, s4.z, w4.z) DOIT(d4.w, s4.w, w4.w)
#undef DOIT
        }
        return;
    }

    // ---- gemm ----
    const int t = threadIdx.x;
    const int w = t >> 6, lane = t & 63;
    const int wr = w >> 1, wc = w & 1;
    const int lr = lane & 15, lk = lane >> 4;
    const int m0 = (blockIdx.x - NSCAN2) * 64;

    f32x4 acc[2][4] = {};

    auto stage = [&](int buf, int k0) {
        char* lA = smem + buf * 8192;
        char* lB = smem + 24576 + buf * 8192;
#pragma unroll
        for (int i = 0; i < 2; ++i) {
            {   // A: 64 rows x 32 f32 = 512 chunks of 16B
                const int o = i * 256 + t;
                const int row = o >> 3, c = o & 7;
                int grow = m0 + row; if (grow > N_NODES - 1) grow = N_NODES - 1;
                const float* g = x + (size_t)grow * F_IN + k0 + ((c ^ (row & 7)) << 2);
                GLOAD_LDS16(g, lA + (i * 256 + w * 64) * 16);
            }
            {   // B: 128 rows x 32 bf16 = 512 chunks of 16B
                const int o = i * 256 + t;
                const int row = o >> 2, c = o & 3;
                const ushort* g = W0t + (size_t)row * F_IN + k0 + ((c ^ ((row >> 1) & 3)) << 3);
                GLOAD_LDS16(g, lB + (i * 256 + w * 64) * 16);
            }
        }
    };

    stage(0, 0);
    stage(1, 32);
    stage(2, 64);            // 12 loads/thread outstanding, 3 tiles deep
#pragma unroll
    for (int kt = 0; kt < 16; ++kt) {
        const int rem = 15 - kt;                 // compile-time (loop unrolled)
        if (rem >= 2)      asm volatile("s_waitcnt vmcnt(8)" ::: "memory");
        else if (rem == 1) asm volatile("s_waitcnt vmcnt(4)" ::: "memory");
        else               asm volatile("s_waitcnt vmcnt(0)" ::: "memory");
        __builtin_amdgcn_s_barrier();            // all waves' tile-kt chunks visible

        const int cur = kt % 3;
        const float*  Af = (const float*)(smem + cur * 8192);
        const ushort* Bf = (const ushort*)(smem + 24576 + cur * 8192);
        short8 a[2], b[4];
#pragma unroll
        for (int mi = 0; mi < 2; ++mi) {
            const int R = wr * 32 + mi * 16 + lr;
            const float* ar = Af + R * 32;
            const f32x4 lo = *(const f32x4*)(ar + (((2 * lk + 0) ^ (R & 7)) << 2));
            const f32x4 hi = *(const f32x4*)(ar + (((2 * lk + 1) ^ (R & 7)) << 2));
            a[mi] = pack8(lo, hi);
        }
#pragma unroll
        for (int ni = 0; ni < 4; ++ni) {
            const int n = wc * 64 + ni * 16 + lr;
            b[ni] = *(const short8*)(Bf + n * 32 + ((lk ^ ((n >> 1) & 3)) << 3));
        }
        asm volatile("s_waitcnt lgkmcnt(0)" ::: "memory");   // my frag reads done
        __builtin_amdgcn_s_barrier();            // everyone's reads done -> buf free

        if (kt <= 12) stage(cur, (kt + 3) * 32); // refill freed buffer (tile kt+3)

#pragma unroll
        for (int mi = 0; mi < 2; ++mi)
#pragma unroll
            for (int ni = 0; ni < 4; ++ni)
                acc[mi][ni] = __builtin_amdgcn_mfma_f32_16x16x32_bf16(
                    a[mi], b[ni], acc[mi][ni], 0, 0, 0);
    }

    // epilogue: acc (col=lr, row=lk*4+r) -> LDS transpose -> coalesced 16B stores
    float* ep = (float*)smem + w * (16 * 68);
#pragma unroll
    for (int mi = 0; mi < 2; ++mi) {
        __syncthreads();
#pragma unroll
        for (int ni = 0; ni < 4; ++ni)
#pragma unroll
            for (int r = 0; r < 4; ++r)
                ep[(lk * 4 + r) * 68 + ni * 16 + lr] = acc[mi][ni][r];
        __syncthreads();
        const int rr = lane >> 2, cq = lane & 3;
        const int grow = m0 + wr * 32 + mi * 16 + rr;
        alignas(16) float vv[16];
#pragma unroll
        for (int j = 0; j < 4; ++j)
            *(f32x4*)&vv[j * 4] = *(const f32x4*)&ep[rr * 68 + cq * 16 + j * 4];
        if (grow < N_NODES) {
            alignas(16) ushort us[16];
#pragma unroll
            for (int jj = 0; jj < 16; ++jj) us[jj] = f2bf(vv[jj]);
            ushort* orow = XW0b + (size_t)grow * HID + wc * 64 + cq * 16;
            *(uint4*)(orow)     = *(const uint4*)&us[0];
            *(uint4*)(orow + 8) = *(const uint4*)&us[8];
        }
    }
}

// ---------------------------------------------------------------------------
// scan 1 (4 edges/thread, streamed esrc/ew): idx-dst edges -> bktA + flag srcs
// ---------------------------------------------------------------------------
__global__ __launch_bounds__(256) void bucket_idx_kernel(const int* __restrict__ esrc,
                                                         const int* __restrict__ edst,
                                                         const float* __restrict__ ew,
                                                         const ushort* __restrict__ jmap,
                                                         int* __restrict__ countsA,
                                                         int2* __restrict__ bktA,
                                                         ushort* __restrict__ flags) {
    const int e0 = (blockIdx.x * 256 + threadIdx.x) * 4;
    if (e0 >= E_NUM) return;
    const int4   d4 = *(const int4*)(edst + e0);
    const int4   s4 = *(const int4*)(esrc + e0);
    const float4 w4 = *(const float4*)(ew + e0);
#define DOIT(DD, SS, WW) { const int rep = jmap[DD]; if (rep) { \
        const int r = rep - 1; const int c = atomicAdd(&countsA[r], 1); \
        if (c < CAP) bktA[(size_t)r * CAP + c] = make_int2(SS, __float_as_int(WW)); \
        flags[SS] = 1; } }
    DOIT(d4.x, s4.x, w4.x) DOIT(d4.y, s4.y, w4.y)
    DOIT(d4.z, s4.z, w4.z) DOIT(d4.w, s4.w, w4.w)
#undef DOIT
}

__global__ __launch_bounds__(256) void compact_kernel(ushort* __restrict__ flags,
                                                      int* __restrict__ list,
                                                      int* __restrict__ nflag) {
    const int n = blockIdx.x * 256 + threadIdx.x;
    if (n < N_NODES && flags[n]) {
        const int s = atomicAdd(nflag, 1);
        if (s < MAXFLAG) { flags[n] = (ushort)(s + 1); list[s] = n; }
        else flags[n] = 0;
    }
}

// ---------------------------------------------------------------------------
// SPMM1+ReLU over compacted flagged nodes; 1 wave/node, 2 cols/lane, unroll-4
// ---------------------------------------------------------------------------
__global__ __launch_bounds__(256) void spmm1_kernel(const ushort* __restrict__ XW0b,
                                                    const int* __restrict__ list,
                                                    const int* __restrict__ nflag,
                                                    const int* __restrict__ countsB,
                                                    const int2* __restrict__ bktB,
                                                    ushort* __restrict__ H) {
    const int lane = threadIdx.x & 63;
    const int nf = *nflag;
    const int nw = gridDim.x * 4;
    for (int wdx = blockIdx.x * 4 + (threadIdx.x >> 6); wdx < nf; wdx += nw) {
        const int n = list[wdx];
        const int deg = min(countsB[wdx], CAP);
        float a0 = 0.f, a1 = 0.f;
        int c = 0;
        for (; c + 3 < deg; c += 4) {             // 4 gathers in flight
            const int2 p0 = bktB[(size_t)wdx * CAP + c];
            const int2 p1 = bktB[(size_t)wdx * CAP + c + 1];
            const int2 p2 = bktB[(size_t)wdx * CAP + c + 2];
            const int2 p3 = bktB[(size_t)wdx * CAP + c + 3];
            const uint v0 = *(const uint*)(XW0b + (size_t)p0.x * HID + 2 * lane);
            const uint v1 = *(const uint*)(XW0b + (size_t)p1.x * HID + 2 * lane);
            const uint v2 = *(const uint*)(XW0b + (size_t)p2.x * HID + 2 * lane);
            const uint v3 = *(const uint*)(XW0b + (size_t)p3.x * HID + 2 * lane);
            const float w0 = __int_as_float(p0.y), w1 = __int_as_float(p1.y);
            const float w2 = __int_as_float(p2.y), w3 = __int_as_float(p3.y);
            a0 += w0 * bf2f((ushort)(v0 & 0xffffu)) + w1 * bf2f((ushort)(v1 & 0xffffu))
                + w2 * bf2f((ushort)(v2 & 0xffffu)) + w3 * bf2f((ushort)(v3 & 0xffffu));
            a1 += w0 * bf2f((ushort)(v0 >> 16))     + w1 * bf2f((ushort)(v1 >> 16))
                + w2 * bf2f((ushort)(v2 >> 16))     + w3 * bf2f((ushort)(v3 >> 16));
        }
        for (; c < deg; ++c) {
            const int2 p = bktB[(size_t)wdx * CAP + c];
            const float wt = __int_as_float(p.y);
            const uint v = *(const uint*)(XW0b + (size_t)p.x * HID + 2 * lane);
            a0 += wt * bf2f((ushort)(v & 0xffffu));
            a1 += wt * bf2f((ushort)(v >> 16));
        }
        const uint o = (uint)f2bf(fmaxf(a0, 0.f)) | ((uint)f2bf(fmaxf(a1, 0.f)) << 16);
        *(uint*)(H + (size_t)n * HID + 2 * lane) = o;
    }
}

// ---------------------------------------------------------------------------
// SPMM2 (idx rows) fused with GEMM2: out[j] = (sum w*H[src]) @ W1
// ---------------------------------------------------------------------------
__global__ __launch_bounds__(64) void spmm2_kernel(const ushort* __restrict__ H,
                                                   const float* __restrict__ W1,
                                                   const int* __restrict__ idx,
                                                   const ushort* __restrict__ jmap,
                                                   const int* __restrict__ countsA,
                                                   const int2* __restrict__ bktA,
                                                   float* __restrict__ outp) {
    __shared__ float aggs[HID];
    const int j = blockIdx.x, lane = threadIdx.x;
    const int r = (int)jmap[idx[j]] - 1;  // rep slot (shared by dup idx entries)
    const int deg = min(countsA[r], CAP);
    float a0 = 0.f, a1 = 0.f;
    for (int c = 0; c < deg; ++c) {
        const int2 p = bktA[(size_t)r * CAP + c];
        const float wt = __int_as_float(p.y);
        const uint v = *(const uint*)(H + (size_t)p.x * HID + 2 * lane);
        a0 += wt * bf2f((ushort)(v & 0xffffu));
        a1 += wt * bf2f((ushort)(v >> 16));
    }
    aggs[2 * lane] = a0; aggs[2 * lane + 1] = a1;
    __syncthreads();
    float s = 0.f;
#pragma unroll 8
    for (int k = 0; k < HID; ++k) s += aggs[k] * W1[k * OUT_F + lane];
    outp[(size_t)j * OUT_F + lane] = s;
}

// ---------------------------------------------------------------------------
extern "C" void kernel_launch(void* const* d_in, const int* in_sizes, int n_in,
                              void* d_out, int out_size, void* d_ws, size_t ws_size,
                              hipStream_t stream) {
    const float* x    = (const float*)d_in[0];
    const float* W0   = (const float*)d_in[1];
    const float* W1   = (const float*)d_in[2];
    const float* ew   = (const float*)d_in[3];
    const int*   esrc = (const int*)d_in[4];
    const int*   edst = (const int*)d_in[5];
    const int*   idx  = (const int*)d_in[6];
    float* outp = (float*)d_out;

    char* ws = (char*)d_ws;
    ushort* XW0b   = (ushort*)(ws);                      // 12,800,000
    ushort* H      = (ushort*)(ws + 12800000);           // 12,800,000
    ushort* W0t    = (ushort*)(ws + 25600000);           //    131,072
    int2*   bktA   = (int2*)  (ws + 25731072);           //    384,000
    int2*   bktB   = (int2*)  (ws + 26115072);           //  7,864,320
    int*    list   = (int*)   (ws + 33979392);           //     81,920
    char*   zbase  = ws + 34061312;                      // zeroed control block
    int*    countsA = (int*)   (zbase);                  //      4,096
    int*    countsB = (int*)   (zbase + 4096);           //     81,920
    ushort* flags   = (ushort*)(zbase + 86016);          //    100,352
    ushort* jmap    = (ushort*)(zbase + 186368);         //    100,352
    int*    nflag   = (int*)   (zbase + 286720);         //        256
    hipMemsetAsync(zbase, 0, 286976, stream);

    prep_kernel       <<<68, 256, 0, stream>>>(W0, W0t, idx, jmap);
    bucket_idx_kernel <<<(E_NUM / 4 + 255) / 256, 256, 0, stream>>>(esrc, edst, ew, jmap, countsA, bktA, flags);
    compact_kernel    <<<(N_NODES + 255) / 256, 256, 0, stream>>>(flags, list, nflag);
    fused_gemm_scan2  <<<NSCAN2 + (N_NODES + 63) / 64, 256, 0, stream>>>(
                          x, W0t, XW0b, esrc, edst, ew, flags, countsB, bktB);
    spmm1_kernel      <<<1024, 256, 0, stream>>>(XW0b, list, nflag, countsB, bktB, H);
    spmm2_kernel      <<<NIDX, 64, 0, stream>>>(H, W1, idx, jmap, countsA, bktA, outp);
}